// Round 1
// baseline (11257.285 us; speedup 1.0000x reference)
//
#include <hip/hip_runtime.h>
#include <hip/hip_bf16.h>
#include <math.h>
#include <stdint.h>

using bf16 = __hip_bfloat16;

__device__ __forceinline__ float b2f(bf16 v){ return __bfloat162float(v); }
__device__ __forceinline__ bf16  f2b(float v){ return __float2bfloat16(v); }
__device__ __forceinline__ float ldf(const float* p){ return *p; }
__device__ __forceinline__ float ldf(const bf16* p){ return __bfloat162float(*p); }

__device__ __forceinline__ float gelu_exact(float x){
  return 0.5f * x * (1.0f + erff(x * 0.7071067811865475f));
}
__device__ __forceinline__ float sigmoidf_(float x){ return 1.0f / (1.0f + expf(-x)); }

// ---------------- threefry2x32 (JAX-compatible) ----------------
__device__ __forceinline__ uint32_t rotl32(uint32_t x, int d){ return (x << d) | (x >> (32 - d)); }

__device__ __forceinline__ void threefry2x32(uint32_t k0, uint32_t k1, uint32_t& x0, uint32_t& x1){
  uint32_t ks2 = k0 ^ k1 ^ 0x1BD11BDAu;
  x0 += k0; x1 += k1;
#define TF_R(r) { x0 += x1; x1 = rotl32(x1, r); x1 ^= x0; }
  TF_R(13) TF_R(15) TF_R(26) TF_R(6)  x0 += k1;  x1 += ks2 + 1u;
  TF_R(17) TF_R(29) TF_R(16) TF_R(24) x0 += ks2; x1 += k0 + 2u;
  TF_R(13) TF_R(15) TF_R(26) TF_R(6)  x0 += k0;  x1 += k1 + 3u;
  TF_R(17) TF_R(29) TF_R(16) TF_R(24) x0 += k1;  x1 += ks2 + 4u;
  TF_R(13) TF_R(15) TF_R(26) TF_R(6)  x0 += ks2; x1 += k0 + 5u;
#undef TF_R
}

// XLA ErfInv32 (Giles) — matches lax.erf_inv for f32
__device__ __forceinline__ float erfinv_f(float x){
  float w = -log1pf(-x * x);
  float p;
  if (w < 5.0f){
    w -= 2.5f;
    p = 2.81022636e-08f;
    p = fmaf(p, w, 3.43273939e-07f);
    p = fmaf(p, w, -3.5233877e-06f);
    p = fmaf(p, w, -4.39150654e-06f);
    p = fmaf(p, w, 0.00021858087f);
    p = fmaf(p, w, -0.00125372503f);
    p = fmaf(p, w, -0.00417768164f);
    p = fmaf(p, w, 0.246640727f);
    p = fmaf(p, w, 1.50140941f);
  } else {
    w = sqrtf(w) - 3.0f;
    p = -0.000200214257f;
    p = fmaf(p, w, 0.000100950558f);
    p = fmaf(p, w, 0.00134934322f);
    p = fmaf(p, w, -0.00367342844f);
    p = fmaf(p, w, 0.00573950773f);
    p = fmaf(p, w, -0.0076224613f);
    p = fmaf(p, w, 0.00943887047f);
    p = fmaf(p, w, 1.00167406f);
    p = fmaf(p, w, 2.83297682f);
  }
  return p * x;
}

// ---------------- direct 3x3 conv + bias + exact GELU ----------------
template<typename TIN, int CIN, int S, int HIN, int WIN>
__global__ void conv3x3_gelu(const TIN* __restrict__ in, const float* __restrict__ w,
                             const float* __restrict__ bias, bf16* __restrict__ out,
                             int N, int COUT){
  constexpr int HOUT = HIN / S, WOUT = WIN / S;
  int idx = blockIdx.x * blockDim.x + threadIdx.x;
  int total = N * COUT * HOUT * WOUT;
  if (idx >= total) return;
  int x  = idx % WOUT;
  int y  = (idx / WOUT) % HOUT;
  int co = (idx / (WOUT * HOUT)) % COUT;
  int n  = idx / (WOUT * HOUT * COUT);

  int iy0 = y * S - 1, ix0 = x * S - 1;
  float acc = bias[co];
  const float* wp = w + co * (CIN * 9);
  const TIN* ip = in + (size_t)n * CIN * (HIN * WIN);
  for (int ci = 0; ci < CIN; ++ci){
    const TIN* p = ip + ci * (HIN * WIN);
    const float* wc = wp + ci * 9;
#pragma unroll
    for (int dy = 0; dy < 3; ++dy){
      int iy = iy0 + dy;
      if ((unsigned)iy >= (unsigned)HIN) continue;
      const TIN* row = p + iy * WIN;
#pragma unroll
      for (int dx = 0; dx < 3; ++dx){
        int ix = ix0 + dx;
        if ((unsigned)ix >= (unsigned)WIN) continue;
        acc = fmaf(ldf(row + ix), wc[dy * 3 + dx], acc);
      }
    }
  }
  out[idx] = f2b(gelu_exact(acc));
}

// ---------------- weight prep ----------------
__global__ void transpose_fcw(const float* __restrict__ w, float* __restrict__ wT){
  int idx = blockIdx.x * 256 + threadIdx.x;           // 4096*256
  if (idx >= 4096 * 256) return;
  int j = idx & 255, k = idx >> 8;
  wT[idx] = w[j * 4096 + k];
}

__global__ void prep_lstm(const float* __restrict__ Wih, const float* __restrict__ Whh,
                          const float* __restrict__ bih, const float* __restrict__ bhh,
                          float* __restrict__ WTih, float* __restrict__ WTwh, float* __restrict__ bsum){
  int idx = blockIdx.x * 256 + threadIdx.x;           // 5*128*512 = 327680
  if (idx < 5 * 128 * 512){
    int j = idx & 511;
    int k = (idx >> 9) & 127;
    int l = idx >> 16;
    WTih[idx] = Wih[(l * 512 + j) * 128 + k];
    WTwh[idx] = Whh[(l * 512 + j) * 128 + k];
  }
  if (idx < 5 * 512) bsum[idx] = bih[idx] + bhh[idx];
}

// ---------------- encoder FC ----------------
__global__ void fc_enc(const bf16* __restrict__ a, const float* __restrict__ wT,
                       const float* __restrict__ fcb, float* __restrict__ ml){
  __shared__ bf16 sA[4][4096];                         // 32 KiB
  int n0 = blockIdx.x * 4;
  for (int idx = threadIdx.x; idx < 4 * 4096; idx += 256){
    int r = idx >> 12, k = idx & 4095;
    sA[r][k] = a[(size_t)(n0 + r) * 4096 + k];
  }
  __syncthreads();
  int j = threadIdx.x;
  float a0 = fcb[j], a1 = a0, a2 = a0, a3 = a0;
#pragma unroll 4
  for (int k = 0; k < 4096; ++k){
    float wv = wT[k * 256 + j];
    a0 = fmaf(b2f(sA[0][k]), wv, a0);
    a1 = fmaf(b2f(sA[1][k]), wv, a1);
    a2 = fmaf(b2f(sA[2][k]), wv, a2);
    a3 = fmaf(b2f(sA[3][k]), wv, a3);
  }
  ml[(n0 + 0) * 256 + j] = a0;
  ml[(n0 + 1) * 256 + j] = a1;
  ml[(n0 + 2) * 256 + j] = a2;
  ml[(n0 + 3) * 256 + j] = a3;
}

// ---------------- reparameterization with in-kernel threefry ----------------
__global__ void reparam_kernel(const float* __restrict__ ml, float* __restrict__ z){
  int i = blockIdx.x * 256 + threadIdx.x;
  if (i >= 133120) return;
  // jax_threefry_partitionable=True path: counts = (hi,lo) of 64-bit iota; size<2^32 -> hi=0
  uint32_t x0 = 0u, x1 = (uint32_t)i;
  threefry2x32(0u, 42u, x0, x1);
  uint32_t bits = x0 ^ x1;
  uint32_t fb = (bits >> 9) | 0x3f800000u;
  float f = __uint_as_float(fb) - 1.0f;                // [0,1)
  const float lo = -0.99999994f;                       // nextafter(-1,0)
  float u = f * 2.0f + lo;                             // (1.0f - lo) rounds to 2.0f in f32
  u = fmaxf(lo, u);
  float eps = 1.41421354f * erfinv_f(u);               // float32(sqrt(2))
  int n = i >> 7, d = i & 127;
  z[i] = fmaf(eps, expf(0.5f * ml[n * 256 + 128 + d]), ml[n * 256 + d]);
}

// ---------------- LSTM wavefront cell ----------------
// cell (l, t=wf-l); 8 blocks/cell x 256 thr; thread = (batch, dim)
__global__ void lstm_wave(const float* __restrict__ z, const float* __restrict__ WTih,
                          const float* __restrict__ WTwh, const float* __restrict__ bsum,
                          float* __restrict__ hbuf, float* __restrict__ cbuf, int wf){
  int l = blockIdx.x >> 3;
  int t = wf - l;
  if (t < 0 || t >= 64) return;
  int b0 = (blockIdx.x & 7) * 2;
  int tid = threadIdx.x;
  int r = tid >> 7, d = tid & 127;
  int b = b0 + r;

  __shared__ float sI[2][128], sH[2][128];
  {
    float iv;
    if (l == 0) iv = z[(b * 65 + t) * 128 + d];
    else        iv = hbuf[(((l - 1) * 64 + t) * 16 + b) * 128 + d];
    sI[r][d] = iv;
    sH[r][d] = (t == 0) ? 0.0f : hbuf[((l * 64 + (t - 1)) * 16 + b) * 128 + d];
  }
  __syncthreads();

  const float* wi = WTih + l * 65536;                  // [k][512]
  const float* wh = WTwh + l * 65536;
  float ai = bsum[l * 512 + d];
  float af = bsum[l * 512 + 128 + d];
  float ag = bsum[l * 512 + 256 + d];
  float ao = bsum[l * 512 + 384 + d];
#pragma unroll 4
  for (int k = 0; k < 128; ++k){
    float iv = sI[r][k], hv = sH[r][k];
    const float* a  = wi + (k << 9);
    const float* bw = wh + (k << 9);
    ai = fmaf(iv, a[d],       fmaf(hv, bw[d],       ai));
    af = fmaf(iv, a[d + 128], fmaf(hv, bw[d + 128], af));
    ag = fmaf(iv, a[d + 256], fmaf(hv, bw[d + 256], ag));
    ao = fmaf(iv, a[d + 384], fmaf(hv, bw[d + 384], ao));
  }
  int ci = (l * 16 + b) * 128 + d;
  float c  = cbuf[ci];
  float cn = sigmoidf_(af) * c + sigmoidf_(ai) * tanhf(ag);
  float hn = sigmoidf_(ao) * tanhf(cn);
  cbuf[ci] = cn;
  hbuf[((l * 64 + t) * 16 + b) * 128 + d] = hn;
}

// ---------------- projection + MSE ----------------
__global__ void pred_loss(const float* __restrict__ hbuf, const float* __restrict__ lin_w,
                          const float* __restrict__ lin_b, const float* __restrict__ z,
                          float* __restrict__ partial){
  int blk = blockIdx.x;                                // 16*61
  int b = blk / 61, i = 3 + blk % 61;
  int tid = threadIdx.x;                               // 128
  __shared__ float h5[128];
  h5[tid] = hbuf[((4 * 64 + i) * 16 + b) * 128 + tid];
  __syncthreads();
  float acc = lin_b[tid];
  const float* wr = lin_w + tid * 128;
#pragma unroll 8
  for (int k = 0; k < 128; ++k) acc = fmaf(h5[k], wr[k], acc);
  float zy = z[(b * 65 + i + 1) * 128 + tid];
  float df = acc - zy;
  float v = df * df;
  for (int off = 32; off > 0; off >>= 1) v += __shfl_down(v, off);
  __shared__ float wsum[2];
  if ((tid & 63) == 0) wsum[tid >> 6] = v;
  __syncthreads();
  if (tid == 0) partial[blk] = wsum[0] + wsum[1];
}

__global__ void loss_final(const float* __restrict__ partial, float* __restrict__ out){
  int tid = threadIdx.x;                               // 256
  float v = 0.0f;
  for (int i = tid; i < 976; i += 256) v += partial[i];
  for (int off = 32; off > 0; off >>= 1) v += __shfl_down(v, off);
  __shared__ float s[4];
  if ((tid & 63) == 0) s[tid >> 6] = v;
  __syncthreads();
  if (tid == 0) out[0] = (s[0] + s[1] + s[2] + s[3]) * (1.0f / 124928.0f);
}

extern "C" void kernel_launch(void* const* d_in, const int* in_sizes, int n_in,
                              void* d_out, int out_size, void* d_ws, size_t ws_size,
                              hipStream_t stream){
  const float* x   = (const float*)d_in[0];
  const float* ew1 = (const float*)d_in[1];  const float* eb1 = (const float*)d_in[2];
  const float* ew2 = (const float*)d_in[3];  const float* eb2 = (const float*)d_in[4];
  const float* ew3 = (const float*)d_in[5];  const float* eb3 = (const float*)d_in[6];
  const float* ew4 = (const float*)d_in[7];  const float* eb4 = (const float*)d_in[8];
  const float* ew5 = (const float*)d_in[9];  const float* eb5 = (const float*)d_in[10];
  const float* fcw = (const float*)d_in[11]; const float* fcb = (const float*)d_in[12];
  // d_in[13..24]: decoder params (dead code in the reference) — unused
  const float* Wih = (const float*)d_in[25]; const float* Whh = (const float*)d_in[26];
  const float* bih = (const float*)d_in[27]; const float* bhh = (const float*)d_in[28];
  const float* lw  = (const float*)d_in[29]; const float* lb  = (const float*)d_in[30];

  char* ws = (char*)d_ws;
  size_t off = 0;
  auto alloc = [&](size_t bytes) -> void* {
    void* p = ws + off;
    off = (off + bytes + 255) & ~(size_t)255;
    return p;
  };
  bf16*  Aa   = (bf16*) alloc(34078720ull * 2);        // ping  (max 1040x32x32x32)
  bf16*  Ab   = (bf16*) alloc(34078720ull * 2);        // pong
  float* fcwT = (float*)alloc(4096ull * 256 * 4);
  float* ml   = (float*)alloc(1040ull * 256 * 4);
  float* zbuf = (float*)alloc(1040ull * 128 * 4);
  float* WTih = (float*)alloc(5ull * 128 * 512 * 4);
  float* WTwh = (float*)alloc(5ull * 128 * 512 * 4);
  float* bsum = (float*)alloc(5ull * 512 * 4);
  float* hbuf = (float*)alloc(5ull * 64 * 16 * 128 * 4);
  float* cbuf = (float*)alloc(5ull * 16 * 128 * 4);
  float* part = (float*)alloc(976ull * 4);

  hipMemsetAsync(cbuf, 0, 5 * 16 * 128 * 4, stream);

  transpose_fcw<<<4096, 256, 0, stream>>>(fcw, fcwT);
  prep_lstm<<<(327680 + 255) / 256, 256, 0, stream>>>(Wih, Whh, bih, bhh, WTih, WTwh, bsum);

  conv3x3_gelu<float, 1, 2, 64, 64><<<(1040 * 32 * 32 * 32 + 255) / 256, 256, 0, stream>>>(x,  ew1, eb1, Aa, 1040, 32);
  conv3x3_gelu<bf16, 32, 1, 32, 32><<<(1040 * 32 * 32 * 32 + 255) / 256, 256, 0, stream>>>(Aa, ew2, eb2, Ab, 1040, 32);
  conv3x3_gelu<bf16, 32, 2, 32, 32><<<(1040 * 64 * 16 * 16 + 255) / 256, 256, 0, stream>>>(Ab, ew3, eb3, Aa, 1040, 64);
  conv3x3_gelu<bf16, 64, 1, 16, 16><<<(1040 * 64 * 16 * 16 + 255) / 256, 256, 0, stream>>>(Aa, ew4, eb4, Ab, 1040, 64);
  conv3x3_gelu<bf16, 64, 2, 16, 16><<<(1040 * 64 * 8 * 8 + 255) / 256, 256, 0, stream>>>(Ab, ew5, eb5, Aa, 1040, 64);

  fc_enc<<<260, 256, 0, stream>>>(Aa, fcwT, fcb, ml);
  reparam_kernel<<<(133120 + 255) / 256, 256, 0, stream>>>(ml, zbuf);

  for (int wf = 0; wf < 68; ++wf)
    lstm_wave<<<40, 256, 0, stream>>>(zbuf, WTih, WTwh, bsum, hbuf, cbuf, wf);

  pred_loss<<<976, 128, 0, stream>>>(hbuf, lw, lb, zbuf, part);
  loss_final<<<1, 256, 0, stream>>>(part, (float*)d_out);
}

// Round 3
// 1450.516 us; speedup vs baseline: 7.7609x; 7.7609x over previous
//
#include <hip/hip_runtime.h>
#include <hip/hip_bf16.h>
#include <math.h>
#include <stdint.h>

using bf16 = __hip_bfloat16;
typedef short bf16x8 __attribute__((ext_vector_type(8)));
typedef float f32x4 __attribute__((ext_vector_type(4)));

__device__ __forceinline__ ushort f2bu(float v){ union{ bf16 h; ushort u; } c; c.h = __float2bfloat16(v); return c.u; }
__device__ __forceinline__ float bu2f(ushort u){ union{ ushort u; bf16 h; } c; c.u = u; return __bfloat162float(c.h); }

__device__ __forceinline__ float gelu_exact(float x){
  return 0.5f * x * (1.0f + erff(x * 0.7071067811865475f));
}
__device__ __forceinline__ float sigmoidf_(float x){ return 1.0f / (1.0f + expf(-x)); }

// ---------------- threefry2x32 (JAX-compatible, verified round 1) ----------------
__device__ __forceinline__ uint32_t rotl32(uint32_t x, int d){ return (x << d) | (x >> (32 - d)); }
__device__ __forceinline__ void threefry2x32(uint32_t k0, uint32_t k1, uint32_t& x0, uint32_t& x1){
  uint32_t ks2 = k0 ^ k1 ^ 0x1BD11BDAu;
  x0 += k0; x1 += k1;
#define TF_R(r) { x0 += x1; x1 = rotl32(x1, r); x1 ^= x0; }
  TF_R(13) TF_R(15) TF_R(26) TF_R(6)  x0 += k1;  x1 += ks2 + 1u;
  TF_R(17) TF_R(29) TF_R(16) TF_R(24) x0 += ks2; x1 += k0 + 2u;
  TF_R(13) TF_R(15) TF_R(26) TF_R(6)  x0 += k0;  x1 += k1 + 3u;
  TF_R(17) TF_R(29) TF_R(16) TF_R(24) x0 += k1;  x1 += ks2 + 4u;
  TF_R(13) TF_R(15) TF_R(26) TF_R(6)  x0 += ks2; x1 += k0 + 5u;
#undef TF_R
}

__device__ __forceinline__ float erfinv_f(float x){
  float w = -log1pf(-x * x);
  float p;
  if (w < 5.0f){
    w -= 2.5f;
    p = 2.81022636e-08f;
    p = fmaf(p, w, 3.43273939e-07f);
    p = fmaf(p, w, -3.5233877e-06f);
    p = fmaf(p, w, -4.39150654e-06f);
    p = fmaf(p, w, 0.00021858087f);
    p = fmaf(p, w, -0.00125372503f);
    p = fmaf(p, w, -0.00417768164f);
    p = fmaf(p, w, 0.246640727f);
    p = fmaf(p, w, 1.50140941f);
  } else {
    w = sqrtf(w) - 3.0f;
    p = -0.000200214257f;
    p = fmaf(p, w, 0.000100950558f);
    p = fmaf(p, w, 0.00134934322f);
    p = fmaf(p, w, -0.00367342844f);
    p = fmaf(p, w, 0.00573950773f);
    p = fmaf(p, w, -0.0076224613f);
    p = fmaf(p, w, 0.00943887047f);
    p = fmaf(p, w, 1.00167406f);
    p = fmaf(p, w, 2.83297682f);
  }
  return p * x;
}

// ---------------- weight prep: [COUT][CIN][3][3] f32 -> bf16 [co][KP], k = tap*CIN+ci, linear ----------------
__global__ void prep_w(const float* __restrict__ w, ushort* __restrict__ dst, int CIN, int COUT, int KP){
  int idx = blockIdx.x * 256 + threadIdx.x;
  if (idx >= COUT * KP) return;
  int co = idx / KP, kl = idx % KP;
  int KT = 9 * CIN;
  ushort v = 0;
  if (kl < KT){
    int tap = kl / CIN, ci = kl % CIN;
    v = f2bu(w[(co * CIN + ci) * 9 + tap]);
  }
  dst[idx] = v;
}

// fc weight f32 transpose (round-1 verified)
__global__ void transpose_fcw(const float* __restrict__ w, float* __restrict__ wT){
  int idx = blockIdx.x * 256 + threadIdx.x;            // 4096*256
  if (idx >= 4096 * 256) return;
  int j = idx & 255, k = idx >> 8;
  wT[idx] = w[j * 4096 + k];
}

__global__ void prep_lstm(const float* __restrict__ Wih, const float* __restrict__ Whh,
                          const float* __restrict__ bih, const float* __restrict__ bhh,
                          float* __restrict__ WTih, float* __restrict__ WTwh, float* __restrict__ bsum){
  int idx = blockIdx.x * 256 + threadIdx.x;            // 5*128*512 = 327680
  if (idx < 5 * 128 * 512){
    int j = idx & 511;
    int k = (idx >> 9) & 127;
    int l = idx >> 16;
    WTih[idx] = Wih[(l * 512 + j) * 128 + k];
    WTwh[idx] = Whh[(l * 512 + j) * 128 + k];
  }
  if (idx < 5 * 512) bsum[idx] = bih[idx] + bhh[idx];
}

// ---------------- conv1: 1->32ch, stride 2, channels-last bf16 out, scalar stores ----------------
__global__ __launch_bounds__(256) void conv1_gelu(const float* __restrict__ x, const float* __restrict__ w,
                                                  const float* __restrict__ b, ushort* __restrict__ out){
  __shared__ float sw[288];
  __shared__ float sb[32];
  int tid = threadIdx.x;
  if (tid < 288) sw[tid] = w[tid];                     // [co*9 + tap]
  if (tid < 32)  sb[tid] = b[tid];
  __syncthreads();
  int gp = blockIdx.x * 256 + tid;                     // 1040*1024 pixels
  int n = gp >> 10, p = gp & 1023;
  int oy = p >> 5, ox = p & 31;
  const float* xim = x + (size_t)n * 4096;
  float patch[9];
#pragma unroll
  for (int dy = 0; dy < 3; ++dy)
#pragma unroll
    for (int dx = 0; dx < 3; ++dx){
      int iy = oy * 2 + dy - 1, ix = ox * 2 + dx - 1;
      bool ok = ((unsigned)iy < 64u) && ((unsigned)ix < 64u);
      patch[dy * 3 + dx] = ok ? xim[iy * 64 + ix] : 0.f;
    }
  ushort* o = out + (size_t)gp * 32;
#pragma unroll
  for (int co = 0; co < 32; ++co){
    float a = sb[co];
#pragma unroll
    for (int t = 0; t < 9; ++t) a = fmaf(patch[t], sw[co * 9 + t], a);
    o[co] = f2bu(gelu_exact(a));
  }
}

// ---------------- implicit-GEMM MFMA conv (3x3, pad 1), channels-last, padded LDS (no swizzle) ----------------
template<int CIN, int COUT, int HOUT, int WOUT, int S, int WAVES, bool NCHW_OUT>
__global__ __launch_bounds__(WAVES * 64) void conv_mfma(const ushort* __restrict__ in, const ushort* __restrict__ wt,
                                                        const float* __restrict__ bias, ushort* __restrict__ out){
  constexpr int HIN = HOUT * S, WIN = WOUT * S;
  constexpr int KT = 9 * CIN;                           // 288 or 576
  constexpr int KP = (CIN == 32) ? 296 : 600;           // padded weight row stride (mult of 8)
  constexpr int CP = CIN + 8;                           // padded per-pixel LDS stride (mult of 8)
  constexpr int PIN = HIN * WIN;
  constexpr int POUT = HOUT * WOUT;
  constexpr int MT = POUT / 16, NT = COUT / 16, MTW = MT / WAVES;
  constexpr int NTH = WAVES * 64;
  constexpr int KS = KT / 32;
  __shared__ __align__(16) ushort sIn[PIN * CP];
  __shared__ __align__(16) ushort sW[COUT * KP];
  int tid = threadIdx.x;

  const ushort* gin = in + (size_t)blockIdx.x * PIN * CIN;
  for (int t = tid; t < PIN * CIN / 8; t += NTH){
    int e = t * 8;
    int ci = e & (CIN - 1);
    int pix = e / CIN;
    *(uint4*)&sIn[pix * CP + ci] = *(const uint4*)(gin + e);
  }
  for (int t = tid; t < COUT * KP / 8; t += NTH)
    *(uint4*)&sW[t * 8] = *(const uint4*)(wt + t * 8);
  __syncthreads();

  int wid = tid >> 6, lane = tid & 63;
  int l15 = lane & 15, lg = lane >> 4;

  int iyb[MTW], ixb[MTW];
#pragma unroll
  for (int m = 0; m < MTW; ++m){
    int mt = m * WAVES + wid;
    int p = mt * 16 + l15;
    iyb[m] = (p / WOUT) * S - 1;
    ixb[m] = (p % WOUT) * S - 1;
  }
  f32x4 acc[MTW][NT] = {};
  float bv[NT];
#pragma unroll
  for (int nt = 0; nt < NT; ++nt) bv[nt] = bias[nt * 16 + l15];

  const bf16x8 ZV = {0,0,0,0,0,0,0,0};
#pragma unroll
  for (int ks = 0; ks < KS; ++ks){
    int tap = (ks * 32) / CIN;                          // lg*8+j stays within one tap
    int dy = tap / 3, dx = tap % 3;
    int cib = (ks * 32) % CIN + lg * 8;                 // channel base within pixel
    bf16x8 bfr[NT];
#pragma unroll
    for (int nt = 0; nt < NT; ++nt){
      int co = nt * 16 + l15;
      bfr[nt] = *(const bf16x8*)&sW[co * KP + ks * 32 + lg * 8];
    }
#pragma unroll
    for (int m = 0; m < MTW; ++m){
      int iy = iyb[m] + dy, ix = ixb[m] + dx;
      bool ok = ((unsigned)iy < (unsigned)HIN) && ((unsigned)ix < (unsigned)WIN);
      int pixi = ok ? (iy * WIN + ix) : 0;
      bf16x8 a = *(const bf16x8*)&sIn[pixi * CP + cib];
      if (!ok) a = ZV;
#pragma unroll
      for (int nt = 0; nt < NT; ++nt)
        acc[m][nt] = __builtin_amdgcn_mfma_f32_16x16x32_bf16(a, bfr[nt], acc[m][nt], 0, 0, 0);
    }
  }

#pragma unroll
  for (int m = 0; m < MTW; ++m){
    int mt = m * WAVES + wid;
#pragma unroll
    for (int nt = 0; nt < NT; ++nt){
      int co = nt * 16 + l15;
#pragma unroll
      for (int r = 0; r < 4; ++r){
        int prow = mt * 16 + lg * 4 + r;                // C/D: col=lane&15, row=(lane>>4)*4+reg
        float v = gelu_exact(acc[m][nt][r] + bv[nt]);
        if (NCHW_OUT)
          out[(size_t)blockIdx.x * POUT * COUT + co * POUT + prow] = f2bu(v);
        else
          out[(size_t)blockIdx.x * POUT * COUT + (size_t)prow * COUT + co] = f2bu(v);
      }
    }
  }
}

// ---------------- encoder FC (round-1 verified: bf16 A, f32 weights) ----------------
__global__ void fc_enc(const ushort* __restrict__ a, const float* __restrict__ wT,
                       const float* __restrict__ fcb, float* __restrict__ ml){
  __shared__ ushort sA[4][4096];                        // 32 KiB
  int n0 = blockIdx.x * 4;
  for (int idx = threadIdx.x; idx < 4 * 4096; idx += 256){
    int r = idx >> 12, k = idx & 4095;
    sA[r][k] = a[(size_t)(n0 + r) * 4096 + k];
  }
  __syncthreads();
  int j = threadIdx.x;
  float a0 = fcb[j], a1 = a0, a2 = a0, a3 = a0;
#pragma unroll 4
  for (int k = 0; k < 4096; ++k){
    float wv = wT[k * 256 + j];
    a0 = fmaf(bu2f(sA[0][k]), wv, a0);
    a1 = fmaf(bu2f(sA[1][k]), wv, a1);
    a2 = fmaf(bu2f(sA[2][k]), wv, a2);
    a3 = fmaf(bu2f(sA[3][k]), wv, a3);
  }
  ml[(n0 + 0) * 256 + j] = a0;
  ml[(n0 + 1) * 256 + j] = a1;
  ml[(n0 + 2) * 256 + j] = a2;
  ml[(n0 + 3) * 256 + j] = a3;
}

// ---------------- reparameterization ----------------
__global__ void reparam_kernel(const float* __restrict__ ml, float* __restrict__ z){
  int i = blockIdx.x * 256 + threadIdx.x;
  if (i >= 133120) return;
  uint32_t x0 = 0u, x1 = (uint32_t)i;
  threefry2x32(0u, 42u, x0, x1);
  uint32_t bits = x0 ^ x1;
  uint32_t fb = (bits >> 9) | 0x3f800000u;
  float f = __uint_as_float(fb) - 1.0f;
  const float lo = -0.99999994f;
  float u = f * 2.0f + lo;
  u = fmaxf(lo, u);
  float eps = 1.41421354f * erfinv_f(u);
  int n = i >> 7, d = i & 127;
  z[i] = fmaf(eps, expf(0.5f * ml[n * 256 + 128 + d]), ml[n * 256 + d]);
}

// ---------------- LSTM wavefront cell ----------------
__global__ void lstm_wave(const float* __restrict__ z, const float* __restrict__ WTih,
                          const float* __restrict__ WTwh, const float* __restrict__ bsum,
                          float* __restrict__ hbuf, float* __restrict__ cbuf, int wf){
  int l = blockIdx.x >> 3;
  int t = wf - l;
  if (t < 0 || t >= 64) return;
  int b0 = (blockIdx.x & 7) * 2;
  int tid = threadIdx.x;
  int r = tid >> 7, d = tid & 127;
  int b = b0 + r;

  __shared__ float sI[2][128], sH[2][128];
  {
    float iv;
    if (l == 0) iv = z[(b * 65 + t) * 128 + d];
    else        iv = hbuf[(((l - 1) * 64 + t) * 16 + b) * 128 + d];
    sI[r][d] = iv;
    sH[r][d] = (t == 0) ? 0.0f : hbuf[((l * 64 + (t - 1)) * 16 + b) * 128 + d];
  }
  __syncthreads();

  const float* wi = WTih + l * 65536;
  const float* wh = WTwh + l * 65536;
  float ai = bsum[l * 512 + d];
  float af = bsum[l * 512 + 128 + d];
  float ag = bsum[l * 512 + 256 + d];
  float ao = bsum[l * 512 + 384 + d];
#pragma unroll 4
  for (int k = 0; k < 128; ++k){
    float iv = sI[r][k], hv = sH[r][k];
    const float* a  = wi + (k << 9);
    const float* bw = wh + (k << 9);
    ai = fmaf(iv, a[d],       fmaf(hv, bw[d],       ai));
    af = fmaf(iv, a[d + 128], fmaf(hv, bw[d + 128], af));
    ag = fmaf(iv, a[d + 256], fmaf(hv, bw[d + 256], ag));
    ao = fmaf(iv, a[d + 384], fmaf(hv, bw[d + 384], ao));
  }
  int ci = (l * 16 + b) * 128 + d;
  float c  = cbuf[ci];
  float cn = sigmoidf_(af) * c + sigmoidf_(ai) * tanhf(ag);
  float hn = sigmoidf_(ao) * tanhf(cn);
  cbuf[ci] = cn;
  hbuf[((l * 64 + t) * 16 + b) * 128 + d] = hn;
}

// ---------------- projection + MSE ----------------
__global__ void pred_loss(const float* __restrict__ hbuf, const float* __restrict__ lin_w,
                          const float* __restrict__ lin_b, const float* __restrict__ z,
                          float* __restrict__ partial){
  int blk = blockIdx.x;                                // 16*61
  int b = blk / 61, i = 3 + blk % 61;
  int tid = threadIdx.x;                               // 128
  __shared__ float h5[128];
  h5[tid] = hbuf[((4 * 64 + i) * 16 + b) * 128 + tid];
  __syncthreads();
  float acc = lin_b[tid];
  const float* wr = lin_w + tid * 128;
#pragma unroll 8
  for (int k = 0; k < 128; ++k) acc = fmaf(h5[k], wr[k], acc);
  float zy = z[(b * 65 + i + 1) * 128 + tid];
  float df = acc - zy;
  float v = df * df;
  for (int off = 32; off > 0; off >>= 1) v += __shfl_down(v, off);
  __shared__ float wsum[2];
  if ((tid & 63) == 0) wsum[tid >> 6] = v;
  __syncthreads();
  if (tid == 0) partial[blk] = wsum[0] + wsum[1];
}

__global__ void loss_final(const float* __restrict__ partial, float* __restrict__ out){
  int tid = threadIdx.x;                               // 256
  float v = 0.0f;
  for (int i = tid; i < 976; i += 256) v += partial[i];
  for (int off = 32; off > 0; off >>= 1) v += __shfl_down(v, off);
  __shared__ float s[4];
  if ((tid & 63) == 0) s[tid >> 6] = v;
  __syncthreads();
  if (tid == 0) out[0] = (s[0] + s[1] + s[2] + s[3]) * (1.0f / 124928.0f);
}

extern "C" void kernel_launch(void* const* d_in, const int* in_sizes, int n_in,
                              void* d_out, int out_size, void* d_ws, size_t ws_size,
                              hipStream_t stream){
  const float* x   = (const float*)d_in[0];
  const float* ew1 = (const float*)d_in[1];  const float* eb1 = (const float*)d_in[2];
  const float* ew2 = (const float*)d_in[3];  const float* eb2 = (const float*)d_in[4];
  const float* ew3 = (const float*)d_in[5];  const float* eb3 = (const float*)d_in[6];
  const float* ew4 = (const float*)d_in[7];  const float* eb4 = (const float*)d_in[8];
  const float* ew5 = (const float*)d_in[9];  const float* eb5 = (const float*)d_in[10];
  const float* fcw = (const float*)d_in[11]; const float* fcb = (const float*)d_in[12];
  // d_in[13..24]: decoder params (dead code in the reference) — unused
  const float* Wih = (const float*)d_in[25]; const float* Whh = (const float*)d_in[26];
  const float* bih = (const float*)d_in[27]; const float* bhh = (const float*)d_in[28];
  const float* lw  = (const float*)d_in[29]; const float* lb  = (const float*)d_in[30];

  char* ws = (char*)d_ws;
  size_t off = 0;
  auto alloc = [&](size_t bytes) -> void* {
    void* p = ws + off;
    off = (off + bytes + 255) & ~(size_t)255;
    return p;
  };
  ushort* bufA = (ushort*)alloc(34078720ull * 2);      // 1040*1024*32 bf16
  ushort* bufB = (ushort*)alloc(34078720ull * 2);
  ushort* wt2  = (ushort*)alloc(32ull * 296 * 2);
  ushort* wt3  = (ushort*)alloc(64ull * 296 * 2);
  ushort* wt4  = (ushort*)alloc(64ull * 600 * 2);
  ushort* wt5  = (ushort*)alloc(64ull * 600 * 2);
  float*  fcwT = (float*) alloc(4096ull * 256 * 4);
  float*  ml   = (float*) alloc(1040ull * 256 * 4);
  float*  zbuf = (float*) alloc(1040ull * 128 * 4);
  float*  WTih = (float*) alloc(5ull * 128 * 512 * 4);
  float*  WTwh = (float*) alloc(5ull * 128 * 512 * 4);
  float*  bsum = (float*) alloc(5ull * 512 * 4);
  float*  hbuf = (float*) alloc(5ull * 64 * 16 * 128 * 4);
  float*  cbuf = (float*) alloc(5ull * 16 * 128 * 4);
  float*  part = (float*) alloc(976ull * 4);

  hipMemsetAsync(cbuf, 0, 5 * 16 * 128 * 4, stream);

  prep_w<<<(32 * 296 + 255) / 256, 256, 0, stream>>>(ew2, wt2, 32, 32, 296);
  prep_w<<<(64 * 296 + 255) / 256, 256, 0, stream>>>(ew3, wt3, 32, 64, 296);
  prep_w<<<(64 * 600 + 255) / 256, 256, 0, stream>>>(ew4, wt4, 64, 64, 600);
  prep_w<<<(64 * 600 + 255) / 256, 256, 0, stream>>>(ew5, wt5, 64, 64, 600);
  transpose_fcw<<<4096, 256, 0, stream>>>(fcw, fcwT);
  prep_lstm<<<(327680 + 255) / 256, 256, 0, stream>>>(Wih, Whh, bih, bhh, WTih, WTwh, bsum);

  conv1_gelu<<<4160, 256, 0, stream>>>(x, ew1, eb1, bufA);
  conv_mfma<32, 32, 32, 32, 1, 8, false><<<1040, 512, 0, stream>>>(bufA, wt2, eb2, bufB);
  conv_mfma<32, 64, 16, 16, 2, 8, false><<<1040, 512, 0, stream>>>(bufB, wt3, eb3, bufA);
  conv_mfma<64, 64, 16, 16, 1, 8, false><<<1040, 512, 0, stream>>>(bufA, wt4, eb4, bufB);
  conv_mfma<64, 64,  8,  8, 2, 4, true ><<<1040, 256, 0, stream>>>(bufB, wt5, eb5, bufA);

  fc_enc<<<260, 256, 0, stream>>>(bufA, fcwT, fcb, ml);
  reparam_kernel<<<(133120 + 255) / 256, 256, 0, stream>>>(ml, zbuf);

  for (int wf = 0; wf < 68; ++wf)
    lstm_wave<<<40, 256, 0, stream>>>(zbuf, WTih, WTwh, bsum, hbuf, cbuf, wf);

  pred_loss<<<976, 128, 0, stream>>>(hbuf, lw, lb, zbuf, part);
  loss_final<<<1, 256, 0, stream>>>(part, (float*)d_out);
}

// Round 6
// 1239.713 us; speedup vs baseline: 9.0806x; 1.1700x over previous
//
#include <hip/hip_runtime.h>
#include <hip/hip_bf16.h>
#include <math.h>
#include <stdint.h>

using bf16 = __hip_bfloat16;
typedef short bf16x8 __attribute__((ext_vector_type(8)));
typedef float f32x4 __attribute__((ext_vector_type(4)));

__device__ __forceinline__ ushort f2bu(float v){ union{ bf16 h; ushort u; } c; c.h = __float2bfloat16(v); return c.u; }
__device__ __forceinline__ float bu2f(ushort u){ union{ ushort u; bf16 h; } c; c.u = u; return __bfloat162float(c.h); }

__device__ __forceinline__ float gelu_exact(float x){
  return 0.5f * x * (1.0f + erff(x * 0.7071067811865475f));
}
__device__ __forceinline__ float sigmoidf_(float x){ return 1.0f / (1.0f + expf(-x)); }

// ---------------- threefry2x32 (JAX-compatible, verified round 1) ----------------
__device__ __forceinline__ uint32_t rotl32(uint32_t x, int d){ return (x << d) | (x >> (32 - d)); }
__device__ __forceinline__ void threefry2x32(uint32_t k0, uint32_t k1, uint32_t& x0, uint32_t& x1){
  uint32_t ks2 = k0 ^ k1 ^ 0x1BD11BDAu;
  x0 += k0; x1 += k1;
#define TF_R(r) { x0 += x1; x1 = rotl32(x1, r); x1 ^= x0; }
  TF_R(13) TF_R(15) TF_R(26) TF_R(6)  x0 += k1;  x1 += ks2 + 1u;
  TF_R(17) TF_R(29) TF_R(16) TF_R(24) x0 += ks2; x1 += k0 + 2u;
  TF_R(13) TF_R(15) TF_R(26) TF_R(6)  x0 += k0;  x1 += k1 + 3u;
  TF_R(17) TF_R(29) TF_R(16) TF_R(24) x0 += k1;  x1 += ks2 + 4u;
  TF_R(13) TF_R(15) TF_R(26) TF_R(6)  x0 += ks2; x1 += k0 + 5u;
#undef TF_R
}

__device__ __forceinline__ float erfinv_f(float x){
  float w = -log1pf(-x * x);
  float p;
  if (w < 5.0f){
    w -= 2.5f;
    p = 2.81022636e-08f;
    p = fmaf(p, w, 3.43273939e-07f);
    p = fmaf(p, w, -3.5233877e-06f);
    p = fmaf(p, w, -4.39150654e-06f);
    p = fmaf(p, w, 0.00021858087f);
    p = fmaf(p, w, -0.00125372503f);
    p = fmaf(p, w, -0.00417768164f);
    p = fmaf(p, w, 0.246640727f);
    p = fmaf(p, w, 1.50140941f);
  } else {
    w = sqrtf(w) - 3.0f;
    p = -0.000200214257f;
    p = fmaf(p, w, 0.000100950558f);
    p = fmaf(p, w, 0.00134934322f);
    p = fmaf(p, w, -0.00367342844f);
    p = fmaf(p, w, 0.00573950773f);
    p = fmaf(p, w, -0.0076224613f);
    p = fmaf(p, w, 0.00943887047f);
    p = fmaf(p, w, 1.00167406f);
    p = fmaf(p, w, 2.83297682f);
  }
  return p * x;
}

// ---------------- weight prep: [COUT][CIN][3][3] f32 -> bf16 [co][KP], k = tap*CIN+ci, linear ----------------
__global__ void prep_w(const float* __restrict__ w, ushort* __restrict__ dst, int CIN, int COUT, int KP){
  int idx = blockIdx.x * 256 + threadIdx.x;
  if (idx >= COUT * KP) return;
  int co = idx / KP, kl = idx % KP;
  int KT = 9 * CIN;
  ushort v = 0;
  if (kl < KT){
    int tap = kl / CIN, ci = kl % CIN;
    v = f2bu(w[(co * CIN + ci) * 9 + tap]);
  }
  dst[idx] = v;
}

// fc weight f32 -> bf16, linear [256][4096]
__global__ void prep_fcb(const float* __restrict__ w, ushort* __restrict__ wb){
  int idx = blockIdx.x * 256 + threadIdx.x;            // 256*4096
  if (idx >= 256 * 4096) return;
  wb[idx] = f2bu(w[idx]);
}

__global__ void prep_lstm(const float* __restrict__ Wih, const float* __restrict__ Whh,
                          const float* __restrict__ bih, const float* __restrict__ bhh,
                          float* __restrict__ WTih, float* __restrict__ WTwh, float* __restrict__ bsum){
  int idx = blockIdx.x * 256 + threadIdx.x;            // 5*128*512 = 327680
  if (idx < 5 * 128 * 512){
    int j = idx & 511;
    int k = (idx >> 9) & 127;
    int l = idx >> 16;
    WTih[idx] = Wih[(l * 512 + j) * 128 + k];
    WTwh[idx] = Whh[(l * 512 + j) * 128 + k];
  }
  if (idx < 5 * 512) bsum[idx] = bih[idx] + bhh[idx];
}

// ---------------- conv1: 1->32ch, stride 2, channels-last bf16 out ----------------
__global__ __launch_bounds__(256) void conv1_gelu(const float* __restrict__ x, const float* __restrict__ w,
                                                  const float* __restrict__ b, ushort* __restrict__ out){
  __shared__ float sw[288];
  __shared__ float sb[32];
  int tid = threadIdx.x;
  if (tid < 288) sw[tid] = w[tid];                     // [co*9 + tap]
  if (tid < 32)  sb[tid] = b[tid];
  __syncthreads();
  int gp = blockIdx.x * 256 + tid;                     // 1040*1024 pixels
  int n = gp >> 10, p = gp & 1023;
  int oy = p >> 5, ox = p & 31;
  const float* xim = x + (size_t)n * 4096;
  float patch[9];
#pragma unroll
  for (int dy = 0; dy < 3; ++dy)
#pragma unroll
    for (int dx = 0; dx < 3; ++dx){
      int iy = oy * 2 + dy - 1, ix = ox * 2 + dx - 1;
      bool ok = ((unsigned)iy < 64u) && ((unsigned)ix < 64u);
      patch[dy * 3 + dx] = ok ? xim[iy * 64 + ix] : 0.f;
    }
  ushort* o = out + (size_t)gp * 32;
#pragma unroll
  for (int co = 0; co < 32; ++co){
    float a = sb[co];
#pragma unroll
    for (int t = 0; t < 9; ++t) a = fmaf(patch[t], sw[co * 9 + t], a);
    o[co] = f2bu(gelu_exact(a));
  }
}

// ---------------- implicit-GEMM MFMA conv (3x3, pad 1), channels-last, padded LDS ----------------
template<int CIN, int COUT, int HOUT, int WOUT, int S, int WAVES, bool NCHW_OUT>
__global__ __launch_bounds__(WAVES * 64) void conv_mfma(const ushort* __restrict__ in, const ushort* __restrict__ wt,
                                                        const float* __restrict__ bias, ushort* __restrict__ out){
  constexpr int HIN = HOUT * S, WIN = WOUT * S;
  constexpr int KT = 9 * CIN;                           // 288 or 576
  constexpr int KP = (CIN == 32) ? 296 : 600;           // padded weight row stride (mult of 8)
  constexpr int CP = CIN + 8;                           // padded per-pixel LDS stride (mult of 8)
  constexpr int PIN = HIN * WIN;
  constexpr int POUT = HOUT * WOUT;
  constexpr int MT = POUT / 16, NT = COUT / 16, MTW = MT / WAVES;
  constexpr int NTH = WAVES * 64;
  constexpr int KS = KT / 32;
  __shared__ __align__(16) ushort sIn[PIN * CP];
  __shared__ __align__(16) ushort sW[COUT * KP];
  int tid = threadIdx.x;

  const ushort* gin = in + (size_t)blockIdx.x * PIN * CIN;
  for (int t = tid; t < PIN * CIN / 8; t += NTH){
    int e = t * 8;
    int ci = e & (CIN - 1);
    int pix = e / CIN;
    *(uint4*)&sIn[pix * CP + ci] = *(const uint4*)(gin + e);
  }
  for (int t = tid; t < COUT * KP / 8; t += NTH)
    *(uint4*)&sW[t * 8] = *(const uint4*)(wt + t * 8);
  __syncthreads();

  int wid = tid >> 6, lane = tid & 63;
  int l15 = lane & 15, lg = lane >> 4;

  int iyb[MTW], ixb[MTW];
#pragma unroll
  for (int m = 0; m < MTW; ++m){
    int mt = m * WAVES + wid;
    int p = mt * 16 + l15;
    iyb[m] = (p / WOUT) * S - 1;
    ixb[m] = (p % WOUT) * S - 1;
  }
  f32x4 acc[MTW][NT] = {};
  float bv[NT];
#pragma unroll
  for (int nt = 0; nt < NT; ++nt) bv[nt] = bias[nt * 16 + l15];

  const bf16x8 ZV = {0,0,0,0,0,0,0,0};
#pragma unroll
  for (int ks = 0; ks < KS; ++ks){
    int tap = (ks * 32) / CIN;                          // lg*8+j stays within one tap
    int dy = tap / 3, dx = tap % 3;
    int cib = (ks * 32) % CIN + lg * 8;                 // channel base within pixel
    bf16x8 bfr[NT];
#pragma unroll
    for (int nt = 0; nt < NT; ++nt){
      int co = nt * 16 + l15;
      bfr[nt] = *(const bf16x8*)&sW[co * KP + ks * 32 + lg * 8];
    }
#pragma unroll
    for (int m = 0; m < MTW; ++m){
      int iy = iyb[m] + dy, ix = ixb[m] + dx;
      bool ok = ((unsigned)iy < (unsigned)HIN) && ((unsigned)ix < (unsigned)WIN);
      int pixi = ok ? (iy * WIN + ix) : 0;
      bf16x8 a = *(const bf16x8*)&sIn[pixi * CP + cib];
      if (!ok) a = ZV;
#pragma unroll
      for (int nt = 0; nt < NT; ++nt)
        acc[m][nt] = __builtin_amdgcn_mfma_f32_16x16x32_bf16(a, bfr[nt], acc[m][nt], 0, 0, 0);
    }
  }

#pragma unroll
  for (int m = 0; m < MTW; ++m){
    int mt = m * WAVES + wid;
#pragma unroll
    for (int nt = 0; nt < NT; ++nt){
      int co = nt * 16 + l15;
#pragma unroll
      for (int r = 0; r < 4; ++r){
        int prow = mt * 16 + lg * 4 + r;                // C/D: col=lane&15, row=(lane>>4)*4+reg
        float v = gelu_exact(acc[m][nt][r] + bv[nt]);
        if (NCHW_OUT)
          out[(size_t)blockIdx.x * POUT * COUT + co * POUT + prow] = f2bu(v);
        else
          out[(size_t)blockIdx.x * POUT * COUT + (size_t)prow * COUT + co] = f2bu(v);
      }
    }
  }
}

// ---------------- encoder FC as MFMA GEMM: ml[1040][256] = A[1040][4096] @ W^T + b ----------------
__global__ __launch_bounds__(256) void fc_mfma(const ushort* __restrict__ A, const ushort* __restrict__ Wb,
                                               const float* __restrict__ fcb, float* __restrict__ ml){
  __shared__ __align__(16) ushort sA[64][72];           // +8 pad
  __shared__ __align__(16) ushort sB[256][72];
  int tid = threadIdx.x;
  int M0 = blockIdx.x * 64;
  int wid = tid >> 6, lane = tid & 63;
  int l15 = lane & 15, lg = lane >> 4;

  f32x4 acc[16] = {};
  for (int kb = 0; kb < 64; ++kb){
    // stage A: 64 rows x 64 k (clamp OOB rows of the 1040-row matrix)
#pragma unroll
    for (int i = 0; i < 2; ++i){
      int t = i * 256 + tid;                            // 512 uint4
      int row = t >> 3, c = t & 7;
      int grow = M0 + row; if (grow > 1039) grow = 1039;
      *(uint4*)&sA[row][c * 8] = *(const uint4*)(A + (size_t)grow * 4096 + kb * 64 + c * 8);
    }
    // stage B: 256 rows x 64 k
#pragma unroll
    for (int i = 0; i < 8; ++i){
      int t = i * 256 + tid;                            // 2048 uint4
      int row = t >> 3, c = t & 7;
      *(uint4*)&sB[row][c * 8] = *(const uint4*)(Wb + (size_t)row * 4096 + kb * 64 + c * 8);
    }
    __syncthreads();
#pragma unroll
    for (int ks = 0; ks < 2; ++ks){
      bf16x8 a = *(const bf16x8*)&sA[wid * 16 + l15][ks * 32 + lg * 8];
#pragma unroll
      for (int nt = 0; nt < 16; ++nt){
        bf16x8 b = *(const bf16x8*)&sB[nt * 16 + l15][ks * 32 + lg * 8];
        acc[nt] = __builtin_amdgcn_mfma_f32_16x16x32_bf16(a, b, acc[nt], 0, 0, 0);
      }
    }
    __syncthreads();
  }
#pragma unroll
  for (int nt = 0; nt < 16; ++nt){
    int j = nt * 16 + l15;
#pragma unroll
    for (int r = 0; r < 4; ++r){
      int row = M0 + wid * 16 + lg * 4 + r;
      if (row < 1040) ml[row * 256 + j] = acc[nt][r] + fcb[j];
    }
  }
}

// ---------------- reparameterization ----------------
__global__ void reparam_kernel(const float* __restrict__ ml, float* __restrict__ z){
  int i = blockIdx.x * 256 + threadIdx.x;
  if (i >= 133120) return;
  uint32_t x0 = 0u, x1 = (uint32_t)i;
  threefry2x32(0u, 42u, x0, x1);
  uint32_t bits = x0 ^ x1;
  uint32_t fb = (bits >> 9) | 0x3f800000u;
  float f = __uint_as_float(fb) - 1.0f;
  const float lo = -0.99999994f;
  float u = f * 2.0f + lo;
  u = fmaxf(lo, u);
  float eps = 1.41421354f * erfinv_f(u);
  int n = i >> 7, d = i & 127;
  // clamp exp arg: inert when ml is correct (|logvar| ~ O(1)); converts any
  // upstream blow-up into a finite, magnitude-informative absmax (not NaN).
  float ex = expf(fminf(0.5f * ml[n * 256 + 128 + d], 60.0f));
  z[i] = fmaf(eps, ex, ml[n * 256 + d]);
}

// ---------------- LSTM wavefront cell (round-3 verified) ----------------
// cell (l, t=wf-l); 8 blocks/cell x 256 thr; thread = (batch, dim)
__global__ void lstm_wave(const float* __restrict__ z, const float* __restrict__ WTih,
                          const float* __restrict__ WTwh, const float* __restrict__ bsum,
                          float* __restrict__ hbuf, float* __restrict__ cbuf, int wf){
  int l = blockIdx.x >> 3;
  int t = wf - l;
  if (t < 0 || t >= 64) return;
  int b0 = (blockIdx.x & 7) * 2;
  int tid = threadIdx.x;
  int r = tid >> 7, d = tid & 127;
  int b = b0 + r;

  __shared__ float sI[2][128], sH[2][128];
  {
    float iv;
    if (l == 0) iv = z[(b * 65 + t) * 128 + d];
    else        iv = hbuf[(((l - 1) * 64 + t) * 16 + b) * 128 + d];
    sI[r][d] = iv;
    sH[r][d] = (t == 0) ? 0.0f : hbuf[((l * 64 + (t - 1)) * 16 + b) * 128 + d];
  }
  __syncthreads();

  const float* wi = WTih + l * 65536;                  // [k][512]
  const float* wh = WTwh + l * 65536;
  float ai = bsum[l * 512 + d];
  float af = bsum[l * 512 + 128 + d];
  float ag = bsum[l * 512 + 256 + d];
  float ao = bsum[l * 512 + 384 + d];
#pragma unroll 4
  for (int k = 0; k < 128; ++k){
    float iv = sI[r][k], hv = sH[r][k];
    const float* a  = wi + (k << 9);
    const float* bw = wh + (k << 9);
    ai = fmaf(iv, a[d],       fmaf(hv, bw[d],       ai));
    af = fmaf(iv, a[d + 128], fmaf(hv, bw[d + 128], af));
    ag = fmaf(iv, a[d + 256], fmaf(hv, bw[d + 256], ag));
    ao = fmaf(iv, a[d + 384], fmaf(hv, bw[d + 384], ao));
  }
  int ci = (l * 16 + b) * 128 + d;
  float c  = cbuf[ci];
  float cn = sigmoidf_(af) * c + sigmoidf_(ai) * tanhf(ag);
  float hn = sigmoidf_(ao) * tanhf(cn);
  cbuf[ci] = cn;
  hbuf[((l * 64 + t) * 16 + b) * 128 + d] = hn;
}

// ---------------- projection + MSE ----------------
__global__ void pred_loss(const float* __restrict__ hbuf, const float* __restrict__ lin_w,
                          const float* __restrict__ lin_b, const float* __restrict__ z,
                          float* __restrict__ partial){
  int blk = blockIdx.x;                                // 16*61
  int b = blk / 61, i = 3 + blk % 61;
  int tid = threadIdx.x;                               // 128
  __shared__ float h5[128];
  h5[tid] = hbuf[((4 * 64 + i) * 16 + b) * 128 + tid];
  __syncthreads();
  float acc = lin_b[tid];
  const float* wr = lin_w + tid * 128;
#pragma unroll 8
  for (int k = 0; k < 128; ++k) acc = fmaf(h5[k], wr[k], acc);
  float zy = z[(b * 65 + i + 1) * 128 + tid];
  float df = acc - zy;
  float v = df * df;
  for (int off = 32; off > 0; off >>= 1) v += __shfl_down(v, off);
  __shared__ float wsum[2];
  if ((tid & 63) == 0) wsum[tid >> 6] = v;
  __syncthreads();
  if (tid == 0) partial[blk] = wsum[0] + wsum[1];
}

__global__ void loss_final(const float* __restrict__ partial, float* __restrict__ out){
  int tid = threadIdx.x;                               // 256
  float v = 0.0f;
  for (int i = tid; i < 976; i += 256) v += partial[i];
  for (int off = 32; off > 0; off >>= 1) v += __shfl_down(v, off);
  __shared__ float s[4];
  if ((tid & 63) == 0) s[tid >> 6] = v;
  __syncthreads();
  if (tid == 0) out[0] = (s[0] + s[1] + s[2] + s[3]) * (1.0f / 124928.0f);
}

extern "C" void kernel_launch(void* const* d_in, const int* in_sizes, int n_in,
                              void* d_out, int out_size, void* d_ws, size_t ws_size,
                              hipStream_t stream){
  const float* x   = (const float*)d_in[0];
  const float* ew1 = (const float*)d_in[1];  const float* eb1 = (const float*)d_in[2];
  const float* ew2 = (const float*)d_in[3];  const float* eb2 = (const float*)d_in[4];
  const float* ew3 = (const float*)d_in[5];  const float* eb3 = (const float*)d_in[6];
  const float* ew4 = (const float*)d_in[7];  const float* eb4 = (const float*)d_in[8];
  const float* ew5 = (const float*)d_in[9];  const float* eb5 = (const float*)d_in[10];
  const float* fcw = (const float*)d_in[11]; const float* fcb = (const float*)d_in[12];
  // d_in[13..24]: decoder params (dead code in the reference) — unused
  const float* Wih = (const float*)d_in[25]; const float* Whh = (const float*)d_in[26];
  const float* bih = (const float*)d_in[27]; const float* bhh = (const float*)d_in[28];
  const float* lw  = (const float*)d_in[29]; const float* lb  = (const float*)d_in[30];

  char* ws = (char*)d_ws;
  size_t off = 0;
  auto alloc = [&](size_t bytes) -> void* {
    void* p = ws + off;
    off = (off + bytes + 255) & ~(size_t)255;
    return p;
  };
  ushort* bufA = (ushort*)alloc(34078720ull * 2);      // 1040*1024*32 bf16
  ushort* bufB = (ushort*)alloc(34078720ull * 2);
  ushort* wt2  = (ushort*)alloc(32ull * 296 * 2);
  ushort* wt3  = (ushort*)alloc(64ull * 296 * 2);
  ushort* wt4  = (ushort*)alloc(64ull * 600 * 2);
  ushort* wt5  = (ushort*)alloc(64ull * 600 * 2);
  ushort* fcwB = (ushort*)alloc(256ull * 4096 * 2);
  float*  ml   = (float*) alloc(1040ull * 256 * 4);
  float*  zbuf = (float*) alloc(1040ull * 128 * 4);
  float*  WTih = (float*) alloc(5ull * 128 * 512 * 4);
  float*  WTwh = (float*) alloc(5ull * 128 * 512 * 4);
  float*  bsum = (float*) alloc(5ull * 512 * 4);
  float*  hbuf = (float*) alloc(5ull * 64 * 16 * 128 * 4);
  float*  cbuf = (float*) alloc(5ull * 16 * 128 * 4);
  float*  part = (float*) alloc(976ull * 4);

  hipMemsetAsync(cbuf, 0, 5 * 16 * 128 * 4, stream);

  prep_w<<<(32 * 296 + 255) / 256, 256, 0, stream>>>(ew2, wt2, 32, 32, 296);
  prep_w<<<(64 * 296 + 255) / 256, 256, 0, stream>>>(ew3, wt3, 32, 64, 296);
  prep_w<<<(64 * 600 + 255) / 256, 256, 0, stream>>>(ew4, wt4, 64, 64, 600);
  prep_w<<<(64 * 600 + 255) / 256, 256, 0, stream>>>(ew5, wt5, 64, 64, 600);
  prep_fcb<<<4096, 256, 0, stream>>>(fcw, fcwB);
  prep_lstm<<<(327680 + 255) / 256, 256, 0, stream>>>(Wih, Whh, bih, bhh, WTih, WTwh, bsum);

  conv1_gelu<<<4160, 256, 0, stream>>>(x, ew1, eb1, bufA);
  conv_mfma<32, 32, 32, 32, 1, 8, false><<<1040, 512, 0, stream>>>(bufA, wt2, eb2, bufB);
  conv_mfma<32, 64, 16, 16, 2, 8, false><<<1040, 512, 0, stream>>>(bufB, wt3, eb3, bufA);
  conv_mfma<64, 64, 16, 16, 1, 8, false><<<1040, 512, 0, stream>>>(bufA, wt4, eb4, bufB);
  conv_mfma<64, 64,  8,  8, 2, 4, true ><<<1040, 256, 0, stream>>>(bufB, wt5, eb5, bufA);

  fc_mfma<<<17, 256, 0, stream>>>(bufA, fcwB, fcb, ml);
  reparam_kernel<<<(133120 + 255) / 256, 256, 0, stream>>>(ml, zbuf);

  for (int wf = 0; wf < 68; ++wf)
    lstm_wave<<<40, 256, 0, stream>>>(zbuf, WTih, WTwh, bsum, hbuf, cbuf, wf);

  pred_loss<<<976, 128, 0, stream>>>(hbuf, lw, lb, zbuf, part);
  loss_final<<<1, 256, 0, stream>>>(part, (float*)d_out);
}

// Round 7
// 980.643 us; speedup vs baseline: 11.4795x; 1.2642x over previous
//
#include <hip/hip_runtime.h>
#include <hip/hip_bf16.h>
#include <math.h>
#include <stdint.h>

using bf16 = __hip_bfloat16;
typedef short bf16x8 __attribute__((ext_vector_type(8)));
typedef float f32x4 __attribute__((ext_vector_type(4)));

__device__ __forceinline__ ushort f2bu(float v){ union{ bf16 h; ushort u; } c; c.h = __float2bfloat16(v); return c.u; }
__device__ __forceinline__ float bu2f(ushort u){ union{ ushort u; bf16 h; } c; c.u = u; return __bfloat162float(c.h); }

__device__ __forceinline__ float gelu_exact(float x){
  return 0.5f * x * (1.0f + erff(x * 0.7071067811865475f));
}
__device__ __forceinline__ float sigmoidf_(float x){ return 1.0f / (1.0f + expf(-x)); }

// ---------------- threefry2x32 (JAX-compatible, verified round 1) ----------------
__device__ __forceinline__ uint32_t rotl32(uint32_t x, int d){ return (x << d) | (x >> (32 - d)); }
__device__ __forceinline__ void threefry2x32(uint32_t k0, uint32_t k1, uint32_t& x0, uint32_t& x1){
  uint32_t ks2 = k0 ^ k1 ^ 0x1BD11BDAu;
  x0 += k0; x1 += k1;
#define TF_R(r) { x0 += x1; x1 = rotl32(x1, r); x1 ^= x0; }
  TF_R(13) TF_R(15) TF_R(26) TF_R(6)  x0 += k1;  x1 += ks2 + 1u;
  TF_R(17) TF_R(29) TF_R(16) TF_R(24) x0 += ks2; x1 += k0 + 2u;
  TF_R(13) TF_R(15) TF_R(26) TF_R(6)  x0 += k0;  x1 += k1 + 3u;
  TF_R(17) TF_R(29) TF_R(16) TF_R(24) x0 += k1;  x1 += ks2 + 4u;
  TF_R(13) TF_R(15) TF_R(26) TF_R(6)  x0 += ks2; x1 += k0 + 5u;
#undef TF_R
}

__device__ __forceinline__ float erfinv_f(float x){
  float w = -log1pf(-x * x);
  float p;
  if (w < 5.0f){
    w -= 2.5f;
    p = 2.81022636e-08f;
    p = fmaf(p, w, 3.43273939e-07f);
    p = fmaf(p, w, -3.5233877e-06f);
    p = fmaf(p, w, -4.39150654e-06f);
    p = fmaf(p, w, 0.00021858087f);
    p = fmaf(p, w, -0.00125372503f);
    p = fmaf(p, w, -0.00417768164f);
    p = fmaf(p, w, 0.246640727f);
    p = fmaf(p, w, 1.50140941f);
  } else {
    w = sqrtf(w) - 3.0f;
    p = -0.000200214257f;
    p = fmaf(p, w, 0.000100950558f);
    p = fmaf(p, w, 0.00134934322f);
    p = fmaf(p, w, -0.00367342844f);
    p = fmaf(p, w, 0.00573950773f);
    p = fmaf(p, w, -0.0076224613f);
    p = fmaf(p, w, 0.00943887047f);
    p = fmaf(p, w, 1.00167406f);
    p = fmaf(p, w, 2.83297682f);
  }
  return p * x;
}

// ---------------- weight prep: [COUT][CIN][3][3] f32 -> bf16 [co][KP], k = tap*CIN+ci, linear ----------------
__global__ void prep_w(const float* __restrict__ w, ushort* __restrict__ dst, int CIN, int COUT, int KP){
  int idx = blockIdx.x * 256 + threadIdx.x;
  if (idx >= COUT * KP) return;
  int co = idx / KP, kl = idx % KP;
  int KT = 9 * CIN;
  ushort v = 0;
  if (kl < KT){
    int tap = kl / CIN, ci = kl % CIN;
    v = f2bu(w[(co * CIN + ci) * 9 + tap]);
  }
  dst[idx] = v;
}

// fc weight f32 -> bf16, linear [256][4096]
__global__ void prep_fcb(const float* __restrict__ w, ushort* __restrict__ wb){
  int idx = blockIdx.x * 256 + threadIdx.x;            // 256*4096
  if (idx >= 256 * 4096) return;
  wb[idx] = f2bu(w[idx]);
}

// LSTM weights packed: W8[l][k][d][8] bf16 = (ih_i, ih_f, ih_g, ih_o, hh_i, hh_f, hh_g, hh_o)
__global__ void prep_lstm8(const float* __restrict__ Wih, const float* __restrict__ Whh,
                           const float* __restrict__ bih, const float* __restrict__ bhh,
                           ushort* __restrict__ W8, float* __restrict__ bsum4){
  int idx = blockIdx.x * 256 + threadIdx.x;            // 5*128*128 = 81920
  if (idx < 81920){
    int d = idx & 127, k = (idx >> 7) & 127, l = idx >> 14;
#pragma unroll
    for (int q = 0; q < 4; ++q){
      W8[(size_t)idx * 8 + q]     = f2bu(Wih[(size_t)(l * 512 + q * 128 + d) * 128 + k]);
      W8[(size_t)idx * 8 + 4 + q] = f2bu(Whh[(size_t)(l * 512 + q * 128 + d) * 128 + k]);
    }
  }
  if (idx < 5 * 128){
    int d = idx & 127, l = idx >> 7;
#pragma unroll
    for (int q = 0; q < 4; ++q)
      bsum4[(l * 128 + d) * 4 + q] = bih[l * 512 + q * 128 + d] + bhh[l * 512 + q * 128 + d];
  }
}

// ---------------- conv1: 1->32ch, stride 2, channels-last bf16 out, coalesced uint4 stores ----------------
// thread = (pixel_local, co_octet): 64 pixels x 4 octets per 256-thread block
__global__ __launch_bounds__(256) void conv1_gelu(const float* __restrict__ x, const float* __restrict__ w,
                                                  const float* __restrict__ b, ushort* __restrict__ out){
  __shared__ float sw[288];
  __shared__ float sb[32];
  int tid = threadIdx.x;
  if (tid < 288) sw[tid] = w[tid];                     // [co*9 + tap]
  if (tid < 32)  sb[tid] = b[tid];
  __syncthreads();
  int pl = tid >> 2, q = tid & 3;
  int gp = blockIdx.x * 64 + pl;                       // 1040*1024 pixels, grid = 16640
  int n = gp >> 10, p = gp & 1023;
  int oy = p >> 5, ox = p & 31;
  const float* xim = x + (size_t)n * 4096;
  float patch[9];
#pragma unroll
  for (int dy = 0; dy < 3; ++dy)
#pragma unroll
    for (int dx = 0; dx < 3; ++dx){
      int iy = oy * 2 + dy - 1, ix = ox * 2 + dx - 1;
      bool ok = ((unsigned)iy < 64u) && ((unsigned)ix < 64u);
      patch[dy * 3 + dx] = ok ? xim[iy * 64 + ix] : 0.f;
    }
  __align__(16) ushort res[8];
#pragma unroll
  for (int j = 0; j < 8; ++j){
    int co = q * 8 + j;
    float a = sb[co];
#pragma unroll
    for (int t = 0; t < 9; ++t) a = fmaf(patch[t], sw[co * 9 + t], a);
    res[j] = f2bu(gelu_exact(a));
  }
  *(uint4*)(out + (size_t)gp * 32 + q * 8) = *(const uint4*)res;   // lane-consecutive 16B
}

// ---------------- implicit-GEMM MFMA conv (3x3, pad 1), channels-last, padded LDS ----------------
template<int CIN, int COUT, int HOUT, int WOUT, int S, int WAVES, bool NCHW_OUT>
__global__ __launch_bounds__(WAVES * 64) void conv_mfma(const ushort* __restrict__ in, const ushort* __restrict__ wt,
                                                        const float* __restrict__ bias, ushort* __restrict__ out){
  constexpr int HIN = HOUT * S, WIN = WOUT * S;
  constexpr int KT = 9 * CIN;                           // 288 or 576
  constexpr int KP = (CIN == 32) ? 296 : 600;           // padded weight row stride (mult of 8)
  constexpr int CP = CIN + 8;                           // padded per-pixel LDS stride (mult of 8)
  constexpr int PIN = HIN * WIN;
  constexpr int POUT = HOUT * WOUT;
  constexpr int MT = POUT / 16, NT = COUT / 16, MTW = MT / WAVES;
  constexpr int NTH = WAVES * 64;
  constexpr int KS = KT / 32;
  __shared__ __align__(16) ushort sIn[PIN * CP];
  __shared__ __align__(16) ushort sW[COUT * KP];
  int tid = threadIdx.x;

  const ushort* gin = in + (size_t)blockIdx.x * PIN * CIN;
  for (int t = tid; t < PIN * CIN / 8; t += NTH){
    int e = t * 8;
    int ci = e & (CIN - 1);
    int pix = e / CIN;
    *(uint4*)&sIn[pix * CP + ci] = *(const uint4*)(gin + e);
  }
  for (int t = tid; t < COUT * KP / 8; t += NTH)
    *(uint4*)&sW[t * 8] = *(const uint4*)(wt + t * 8);
  __syncthreads();

  int wid = tid >> 6, lane = tid & 63;
  int l15 = lane & 15, lg = lane >> 4;

  int iyb[MTW], ixb[MTW];
#pragma unroll
  for (int m = 0; m < MTW; ++m){
    int mt = m * WAVES + wid;
    int p = mt * 16 + l15;
    iyb[m] = (p / WOUT) * S - 1;
    ixb[m] = (p % WOUT) * S - 1;
  }
  f32x4 acc[MTW][NT] = {};
  float bv[NT];
#pragma unroll
  for (int nt = 0; nt < NT; ++nt) bv[nt] = bias[nt * 16 + l15];

  const bf16x8 ZV = {0,0,0,0,0,0,0,0};
#pragma unroll
  for (int ks = 0; ks < KS; ++ks){
    int tap = (ks * 32) / CIN;                          // lg*8+j stays within one tap
    int dy = tap / 3, dx = tap % 3;
    int cib = (ks * 32) % CIN + lg * 8;                 // channel base within pixel
    bf16x8 bfr[NT];
#pragma unroll
    for (int nt = 0; nt < NT; ++nt){
      int co = nt * 16 + l15;
      bfr[nt] = *(const bf16x8*)&sW[co * KP + ks * 32 + lg * 8];
    }
#pragma unroll
    for (int m = 0; m < MTW; ++m){
      int iy = iyb[m] + dy, ix = ixb[m] + dx;
      bool ok = ((unsigned)iy < (unsigned)HIN) && ((unsigned)ix < (unsigned)WIN);
      int pixi = ok ? (iy * WIN + ix) : 0;
      bf16x8 a = *(const bf16x8*)&sIn[pixi * CP + cib];
      if (!ok) a = ZV;
#pragma unroll
      for (int nt = 0; nt < NT; ++nt)
        acc[m][nt] = __builtin_amdgcn_mfma_f32_16x16x32_bf16(a, bfr[nt], acc[m][nt], 0, 0, 0);
    }
  }

  if constexpr (!NCHW_OUT){
    // LDS-staged epilogue: one 128-row group per m-iter, then coalesced flat copy
    constexpr int RG = 16 * WAVES;                      // rows per group (128)
    __shared__ ushort sOut[RG * COUT];                  // 16 KB
    size_t obase = (size_t)blockIdx.x * POUT * COUT;
#pragma unroll
    for (int m = 0; m < MTW; ++m){
      if (m) __syncthreads();                           // prev copy done before overwrite
#pragma unroll
      for (int nt = 0; nt < NT; ++nt){
        int co = nt * 16 + l15;
#pragma unroll
        for (int r = 0; r < 4; ++r){
          int rl = wid * 16 + lg * 4 + r;               // row within group
          sOut[rl * COUT + co] = f2bu(gelu_exact(acc[m][nt][r] + bv[nt]));
        }
      }
      __syncthreads();
      for (int t = tid; t < RG * COUT / 8; t += NTH)
        *(uint4*)(out + obase + (size_t)m * RG * COUT + t * 8) = *(const uint4*)&sOut[t * 8];
    }
  } else {
#pragma unroll
    for (int m = 0; m < MTW; ++m){
      int mt = m * WAVES + wid;
#pragma unroll
      for (int nt = 0; nt < NT; ++nt){
        int co = nt * 16 + l15;
#pragma unroll
        for (int r = 0; r < 4; ++r){
          int prow = mt * 16 + lg * 4 + r;              // C/D: col=lane&15, row=(lane>>4)*4+reg
          float v = gelu_exact(acc[m][nt][r] + bv[nt]);
          out[(size_t)blockIdx.x * POUT * COUT + co * POUT + prow] = f2bu(v);
        }
      }
    }
  }
}

// ---------------- encoder FC as MFMA GEMM: ml[1040][256] = A[1040][4096] @ W^T + b ----------------
__global__ __launch_bounds__(256) void fc_mfma(const ushort* __restrict__ A, const ushort* __restrict__ Wb,
                                               const float* __restrict__ fcb, float* __restrict__ ml){
  __shared__ __align__(16) ushort sA[64][72];           // +8 pad
  __shared__ __align__(16) ushort sB[256][72];
  int tid = threadIdx.x;
  int M0 = blockIdx.x * 64;
  int wid = tid >> 6, lane = tid & 63;
  int l15 = lane & 15, lg = lane >> 4;

  f32x4 acc[16] = {};
  for (int kb = 0; kb < 64; ++kb){
#pragma unroll
    for (int i = 0; i < 2; ++i){
      int t = i * 256 + tid;                            // 512 uint4
      int row = t >> 3, c = t & 7;
      int grow = M0 + row; if (grow > 1039) grow = 1039;
      *(uint4*)&sA[row][c * 8] = *(const uint4*)(A + (size_t)grow * 4096 + kb * 64 + c * 8);
    }
#pragma unroll
    for (int i = 0; i < 8; ++i){
      int t = i * 256 + tid;                            // 2048 uint4
      int row = t >> 3, c = t & 7;
      *(uint4*)&sB[row][c * 8] = *(const uint4*)(Wb + (size_t)row * 4096 + kb * 64 + c * 8);
    }
    __syncthreads();
#pragma unroll
    for (int ks = 0; ks < 2; ++ks){
      bf16x8 a = *(const bf16x8*)&sA[wid * 16 + l15][ks * 32 + lg * 8];
#pragma unroll
      for (int nt = 0; nt < 16; ++nt){
        bf16x8 b = *(const bf16x8*)&sB[nt * 16 + l15][ks * 32 + lg * 8];
        acc[nt] = __builtin_amdgcn_mfma_f32_16x16x32_bf16(a, b, acc[nt], 0, 0, 0);
      }
    }
    __syncthreads();
  }
#pragma unroll
  for (int nt = 0; nt < 16; ++nt){
    int j = nt * 16 + l15;
#pragma unroll
    for (int r = 0; r < 4; ++r){
      int row = M0 + wid * 16 + lg * 4 + r;
      if (row < 1040) ml[row * 256 + j] = acc[nt][r] + fcb[j];
    }
  }
}

// ---------------- reparameterization ----------------
__global__ void reparam_kernel(const float* __restrict__ ml, float* __restrict__ z){
  int i = blockIdx.x * 256 + threadIdx.x;
  if (i >= 133120) return;
  uint32_t x0 = 0u, x1 = (uint32_t)i;
  threefry2x32(0u, 42u, x0, x1);
  uint32_t bits = x0 ^ x1;
  uint32_t fb = (bits >> 9) | 0x3f800000u;
  float f = __uint_as_float(fb) - 1.0f;
  const float lo = -0.99999994f;
  float u = f * 2.0f + lo;
  u = fmaxf(lo, u);
  float eps = 1.41421354f * erfinv_f(u);
  int n = i >> 7, d = i & 127;
  float ex = expf(fminf(0.5f * ml[n * 256 + 128 + d], 60.0f));   // clamp inert when ml correct
  z[i] = fmaf(eps, ex, ml[n * 256 + d]);
}

// ---------------- LSTM wavefront cell (round-3 verified structure; packed bf16 weights) ----------------
__global__ void lstm_wave(const float* __restrict__ z, const ushort* __restrict__ W8,
                          const float* __restrict__ bsum4,
                          float* __restrict__ hbuf, float* __restrict__ cbuf, int wf){
  int l = blockIdx.x >> 3;
  int t = wf - l;
  if (t < 0 || t >= 64) return;
  int b0 = (blockIdx.x & 7) * 2;
  int tid = threadIdx.x;
  int r = tid >> 7, d = tid & 127;
  int b = b0 + r;

  __shared__ float sI[2][128], sH[2][128];
  {
    float iv;
    if (l == 0) iv = z[(b * 65 + t) * 128 + d];
    else        iv = hbuf[(((l - 1) * 64 + t) * 16 + b) * 128 + d];
    sI[r][d] = iv;
    sH[r][d] = (t == 0) ? 0.0f : hbuf[((l * 64 + (t - 1)) * 16 + b) * 128 + d];
  }
  __syncthreads();

  const ushort* w8 = W8 + (size_t)l * 131072;           // 128k x 128d x 8
  f32x4 bs = *(const f32x4*)&bsum4[(l * 128 + d) * 4];
  float ai = bs[0], af = bs[1], ag = bs[2], ao = bs[3];
#pragma unroll 4
  for (int k = 0; k < 128; ++k){
    float iv = sI[r][k], hv = sH[r][k];
    bf16x8 wv = *(const bf16x8*)&w8[(k * 128 + d) * 8];
    ai = fmaf(iv, bu2f((ushort)wv[0]), fmaf(hv, bu2f((ushort)wv[4]), ai));
    af = fmaf(iv, bu2f((ushort)wv[1]), fmaf(hv, bu2f((ushort)wv[5]), af));
    ag = fmaf(iv, bu2f((ushort)wv[2]), fmaf(hv, bu2f((ushort)wv[6]), ag));
    ao = fmaf(iv, bu2f((ushort)wv[3]), fmaf(hv, bu2f((ushort)wv[7]), ao));
  }
  int ci = (l * 16 + b) * 128 + d;
  float c  = cbuf[ci];
  float cn = sigmoidf_(af) * c + sigmoidf_(ai) * tanhf(ag);
  float hn = sigmoidf_(ao) * tanhf(cn);
  cbuf[ci] = cn;
  hbuf[((l * 64 + t) * 16 + b) * 128 + d] = hn;
}

// ---------------- projection + MSE ----------------
__global__ void pred_loss(const float* __restrict__ hbuf, const float* __restrict__ lin_w,
                          const float* __restrict__ lin_b, const float* __restrict__ z,
                          float* __restrict__ partial){
  int blk = blockIdx.x;                                // 16*61
  int b = blk / 61, i = 3 + blk % 61;
  int tid = threadIdx.x;                               // 128
  __shared__ float h5[128];
  h5[tid] = hbuf[((4 * 64 + i) * 16 + b) * 128 + tid];
  __syncthreads();
  float acc = lin_b[tid];
  const float* wr = lin_w + tid * 128;
#pragma unroll 8
  for (int k = 0; k < 128; ++k) acc = fmaf(h5[k], wr[k], acc);
  float zy = z[(b * 65 + i + 1) * 128 + tid];
  float df = acc - zy;
  float v = df * df;
  for (int off = 32; off > 0; off >>= 1) v += __shfl_down(v, off);
  __shared__ float wsum[2];
  if ((tid & 63) == 0) wsum[tid >> 6] = v;
  __syncthreads();
  if (tid == 0) partial[blk] = wsum[0] + wsum[1];
}

__global__ void loss_final(const float* __restrict__ partial, float* __restrict__ out){
  int tid = threadIdx.x;                               // 256
  float v = 0.0f;
  for (int i = tid; i < 976; i += 256) v += partial[i];
  for (int off = 32; off > 0; off >>= 1) v += __shfl_down(v, off);
  __shared__ float s[4];
  if ((tid & 63) == 0) s[tid >> 6] = v;
  __syncthreads();
  if (tid == 0) out[0] = (s[0] + s[1] + s[2] + s[3]) * (1.0f / 124928.0f);
}

extern "C" void kernel_launch(void* const* d_in, const int* in_sizes, int n_in,
                              void* d_out, int out_size, void* d_ws, size_t ws_size,
                              hipStream_t stream){
  const float* x   = (const float*)d_in[0];
  const float* ew1 = (const float*)d_in[1];  const float* eb1 = (const float*)d_in[2];
  const float* ew2 = (const float*)d_in[3];  const float* eb2 = (const float*)d_in[4];
  const float* ew3 = (const float*)d_in[5];  const float* eb3 = (const float*)d_in[6];
  const float* ew4 = (const float*)d_in[7];  const float* eb4 = (const float*)d_in[8];
  const float* ew5 = (const float*)d_in[9];  const float* eb5 = (const float*)d_in[10];
  const float* fcw = (const float*)d_in[11]; const float* fcb = (const float*)d_in[12];
  // d_in[13..24]: decoder params (dead code in the reference) — unused
  const float* Wih = (const float*)d_in[25]; const float* Whh = (const float*)d_in[26];
  const float* bih = (const float*)d_in[27]; const float* bhh = (const float*)d_in[28];
  const float* lw  = (const float*)d_in[29]; const float* lb  = (const float*)d_in[30];

  char* ws = (char*)d_ws;
  size_t off = 0;
  auto alloc = [&](size_t bytes) -> void* {
    void* p = ws + off;
    off = (off + bytes + 255) & ~(size_t)255;
    return p;
  };
  ushort* bufA  = (ushort*)alloc(34078720ull * 2);     // 1040*1024*32 bf16
  ushort* bufB  = (ushort*)alloc(34078720ull * 2);
  ushort* wt2   = (ushort*)alloc(32ull * 296 * 2);
  ushort* wt3   = (ushort*)alloc(64ull * 296 * 2);
  ushort* wt4   = (ushort*)alloc(64ull * 600 * 2);
  ushort* wt5   = (ushort*)alloc(64ull * 600 * 2);
  ushort* fcwB  = (ushort*)alloc(256ull * 4096 * 2);
  ushort* W8    = (ushort*)alloc(5ull * 131072 * 2);
  float*  bsum4 = (float*) alloc(5ull * 512 * 4);
  float*  ml    = (float*) alloc(1040ull * 256 * 4);
  float*  zbuf  = (float*) alloc(1040ull * 128 * 4);
  float*  hbuf  = (float*) alloc(5ull * 64 * 16 * 128 * 4);
  float*  cbuf  = (float*) alloc(5ull * 16 * 128 * 4);
  float*  part  = (float*) alloc(976ull * 4);

  hipMemsetAsync(cbuf, 0, 5 * 16 * 128 * 4, stream);

  prep_w<<<(32 * 296 + 255) / 256, 256, 0, stream>>>(ew2, wt2, 32, 32, 296);
  prep_w<<<(64 * 296 + 255) / 256, 256, 0, stream>>>(ew3, wt3, 32, 64, 296);
  prep_w<<<(64 * 600 + 255) / 256, 256, 0, stream>>>(ew4, wt4, 64, 64, 600);
  prep_w<<<(64 * 600 + 255) / 256, 256, 0, stream>>>(ew5, wt5, 64, 64, 600);
  prep_fcb<<<4096, 256, 0, stream>>>(fcw, fcwB);
  prep_lstm8<<<320, 256, 0, stream>>>(Wih, Whh, bih, bhh, W8, bsum4);

  conv1_gelu<<<16640, 256, 0, stream>>>(x, ew1, eb1, bufA);
  conv_mfma<32, 32, 32, 32, 1, 8, false><<<1040, 512, 0, stream>>>(bufA, wt2, eb2, bufB);
  conv_mfma<32, 64, 16, 16, 2, 8, false><<<1040, 512, 0, stream>>>(bufB, wt3, eb3, bufA);
  conv_mfma<64, 64, 16, 16, 1, 8, false><<<1040, 512, 0, stream>>>(bufA, wt4, eb4, bufB);
  conv_mfma<64, 64,  8,  8, 2, 4, true ><<<1040, 256, 0, stream>>>(bufB, wt5, eb5, bufA);

  fc_mfma<<<17, 256, 0, stream>>>(bufA, fcwB, fcb, ml);
  reparam_kernel<<<(133120 + 255) / 256, 256, 0, stream>>>(ml, zbuf);

  for (int wf = 0; wf < 68; ++wf)
    lstm_wave<<<40, 256, 0, stream>>>(zbuf, W8, bsum4, hbuf, cbuf, wf);

  pred_loss<<<976, 128, 0, stream>>>(hbuf, lw, lb, zbuf, part);
  loss_final<<<1, 256, 0, stream>>>(part, (float*)d_out);
}

// Round 8
// 975.089 us; speedup vs baseline: 11.5449x; 1.0057x over previous
//
#include <hip/hip_runtime.h>
#include <hip/hip_bf16.h>
#include <hip/hip_cooperative_groups.h>
#include <math.h>
#include <stdint.h>

namespace cg = cooperative_groups;

using bf16 = __hip_bfloat16;
typedef short bf16x8 __attribute__((ext_vector_type(8)));
typedef float f32x4 __attribute__((ext_vector_type(4)));

__device__ __forceinline__ ushort f2bu(float v){ union{ bf16 h; ushort u; } c; c.h = __float2bfloat16(v); return c.u; }
__device__ __forceinline__ float bu2f(ushort u){ union{ ushort u; bf16 h; } c; c.u = u; return __bfloat162float(c.h); }

__device__ __forceinline__ float gelu_exact(float x){
  return 0.5f * x * (1.0f + erff(x * 0.7071067811865475f));
}
__device__ __forceinline__ float sigmoidf_(float x){ return 1.0f / (1.0f + expf(-x)); }

// ---------------- threefry2x32 (JAX-compatible, verified round 1) ----------------
__device__ __forceinline__ uint32_t rotl32(uint32_t x, int d){ return (x << d) | (x >> (32 - d)); }
__device__ __forceinline__ void threefry2x32(uint32_t k0, uint32_t k1, uint32_t& x0, uint32_t& x1){
  uint32_t ks2 = k0 ^ k1 ^ 0x1BD11BDAu;
  x0 += k0; x1 += k1;
#define TF_R(r) { x0 += x1; x1 = rotl32(x1, r); x1 ^= x0; }
  TF_R(13) TF_R(15) TF_R(26) TF_R(6)  x0 += k1;  x1 += ks2 + 1u;
  TF_R(17) TF_R(29) TF_R(16) TF_R(24) x0 += ks2; x1 += k0 + 2u;
  TF_R(13) TF_R(15) TF_R(26) TF_R(6)  x0 += k0;  x1 += k1 + 3u;
  TF_R(17) TF_R(29) TF_R(16) TF_R(24) x0 += k1;  x1 += ks2 + 4u;
  TF_R(13) TF_R(15) TF_R(26) TF_R(6)  x0 += ks2; x1 += k0 + 5u;
#undef TF_R
}

__device__ __forceinline__ float erfinv_f(float x){
  float w = -log1pf(-x * x);
  float p;
  if (w < 5.0f){
    w -= 2.5f;
    p = 2.81022636e-08f;
    p = fmaf(p, w, 3.43273939e-07f);
    p = fmaf(p, w, -3.5233877e-06f);
    p = fmaf(p, w, -4.39150654e-06f);
    p = fmaf(p, w, 0.00021858087f);
    p = fmaf(p, w, -0.00125372503f);
    p = fmaf(p, w, -0.00417768164f);
    p = fmaf(p, w, 0.246640727f);
    p = fmaf(p, w, 1.50140941f);
  } else {
    w = sqrtf(w) - 3.0f;
    p = -0.000200214257f;
    p = fmaf(p, w, 0.000100950558f);
    p = fmaf(p, w, 0.00134934322f);
    p = fmaf(p, w, -0.00367342844f);
    p = fmaf(p, w, 0.00573950773f);
    p = fmaf(p, w, -0.0076224613f);
    p = fmaf(p, w, 0.00943887047f);
    p = fmaf(p, w, 1.00167406f);
    p = fmaf(p, w, 2.83297682f);
  }
  return p * x;
}

// ---------------- weight prep: [COUT][CIN][3][3] f32 -> bf16 [co][KP], k = tap*CIN+ci, linear ----------------
__global__ void prep_w(const float* __restrict__ w, ushort* __restrict__ dst, int CIN, int COUT, int KP){
  int idx = blockIdx.x * 256 + threadIdx.x;
  if (idx >= COUT * KP) return;
  int co = idx / KP, kl = idx % KP;
  int KT = 9 * CIN;
  ushort v = 0;
  if (kl < KT){
    int tap = kl / CIN, ci = kl % CIN;
    v = f2bu(w[(co * CIN + ci) * 9 + tap]);
  }
  dst[idx] = v;
}

// fc weight f32 -> bf16, linear [256][4096]
__global__ void prep_fcb(const float* __restrict__ w, ushort* __restrict__ wb){
  int idx = blockIdx.x * 256 + threadIdx.x;            // 256*4096
  if (idx >= 256 * 4096) return;
  wb[idx] = f2bu(w[idx]);
}

// LSTM weights packed: W8[l][k][d][8] bf16 = (ih_i, ih_f, ih_g, ih_o, hh_i, hh_f, hh_g, hh_o)
__global__ void prep_lstm8(const float* __restrict__ Wih, const float* __restrict__ Whh,
                           const float* __restrict__ bih, const float* __restrict__ bhh,
                           ushort* __restrict__ W8, float* __restrict__ bsum4){
  int idx = blockIdx.x * 256 + threadIdx.x;            // 5*128*128 = 81920
  if (idx < 81920){
    int d = idx & 127, k = (idx >> 7) & 127, l = idx >> 14;
#pragma unroll
    for (int q = 0; q < 4; ++q){
      W8[(size_t)idx * 8 + q]     = f2bu(Wih[(size_t)(l * 512 + q * 128 + d) * 128 + k]);
      W8[(size_t)idx * 8 + 4 + q] = f2bu(Whh[(size_t)(l * 512 + q * 128 + d) * 128 + k]);
    }
  }
  if (idx < 5 * 128){
    int d = idx & 127, l = idx >> 7;
#pragma unroll
    for (int q = 0; q < 4; ++q)
      bsum4[(l * 128 + d) * 4 + q] = bih[l * 512 + q * 128 + d] + bhh[l * 512 + q * 128 + d];
  }
}

// ---------------- conv1: 1->32ch, stride 2, channels-last bf16 out, coalesced uint4 stores ----------------
__global__ __launch_bounds__(256) void conv1_gelu(const float* __restrict__ x, const float* __restrict__ w,
                                                  const float* __restrict__ b, ushort* __restrict__ out){
  __shared__ float sw[288];
  __shared__ float sb[32];
  int tid = threadIdx.x;
  if (tid < 288) sw[tid] = w[tid];                     // [co*9 + tap]
  if (tid < 32)  sb[tid] = b[tid];
  __syncthreads();
  int pl = tid >> 2, q = tid & 3;
  int gp = blockIdx.x * 64 + pl;                       // 1040*1024 pixels, grid = 16640
  int n = gp >> 10, p = gp & 1023;
  int oy = p >> 5, ox = p & 31;
  const float* xim = x + (size_t)n * 4096;
  float patch[9];
#pragma unroll
  for (int dy = 0; dy < 3; ++dy)
#pragma unroll
    for (int dx = 0; dx < 3; ++dx){
      int iy = oy * 2 + dy - 1, ix = ox * 2 + dx - 1;
      bool ok = ((unsigned)iy < 64u) && ((unsigned)ix < 64u);
      patch[dy * 3 + dx] = ok ? xim[iy * 64 + ix] : 0.f;
    }
  __align__(16) ushort res[8];
#pragma unroll
  for (int j = 0; j < 8; ++j){
    int co = q * 8 + j;
    float a = sb[co];
#pragma unroll
    for (int t = 0; t < 9; ++t) a = fmaf(patch[t], sw[co * 9 + t], a);
    res[j] = f2bu(gelu_exact(a));
  }
  *(uint4*)(out + (size_t)gp * 32 + q * 8) = *(const uint4*)res;
}

// ---------------- implicit-GEMM MFMA conv (3x3, pad 1), channels-last, padded LDS ----------------
template<int CIN, int COUT, int HOUT, int WOUT, int S, int WAVES, bool NCHW_OUT>
__global__ __launch_bounds__(WAVES * 64) void conv_mfma(const ushort* __restrict__ in, const ushort* __restrict__ wt,
                                                        const float* __restrict__ bias, ushort* __restrict__ out){
  constexpr int HIN = HOUT * S, WIN = WOUT * S;
  constexpr int KT = 9 * CIN;
  constexpr int KP = (CIN == 32) ? 296 : 600;
  constexpr int CP = CIN + 8;
  constexpr int PIN = HIN * WIN;
  constexpr int POUT = HOUT * WOUT;
  constexpr int MT = POUT / 16, NT = COUT / 16, MTW = MT / WAVES;
  constexpr int NTH = WAVES * 64;
  constexpr int KS = KT / 32;
  __shared__ __align__(16) ushort sIn[PIN * CP];
  __shared__ __align__(16) ushort sW[COUT * KP];
  int tid = threadIdx.x;

  const ushort* gin = in + (size_t)blockIdx.x * PIN * CIN;
  for (int t = tid; t < PIN * CIN / 8; t += NTH){
    int e = t * 8;
    int ci = e & (CIN - 1);
    int pix = e / CIN;
    *(uint4*)&sIn[pix * CP + ci] = *(const uint4*)(gin + e);
  }
  for (int t = tid; t < COUT * KP / 8; t += NTH)
    *(uint4*)&sW[t * 8] = *(const uint4*)(wt + t * 8);
  __syncthreads();

  int wid = tid >> 6, lane = tid & 63;
  int l15 = lane & 15, lg = lane >> 4;

  int iyb[MTW], ixb[MTW];
#pragma unroll
  for (int m = 0; m < MTW; ++m){
    int mt = m * WAVES + wid;
    int p = mt * 16 + l15;
    iyb[m] = (p / WOUT) * S - 1;
    ixb[m] = (p % WOUT) * S - 1;
  }
  f32x4 acc[MTW][NT] = {};
  float bv[NT];
#pragma unroll
  for (int nt = 0; nt < NT; ++nt) bv[nt] = bias[nt * 16 + l15];

  const bf16x8 ZV = {0,0,0,0,0,0,0,0};
#pragma unroll
  for (int ks = 0; ks < KS; ++ks){
    int tap = (ks * 32) / CIN;
    int dy = tap / 3, dx = tap % 3;
    int cib = (ks * 32) % CIN + lg * 8;
    bf16x8 bfr[NT];
#pragma unroll
    for (int nt = 0; nt < NT; ++nt){
      int co = nt * 16 + l15;
      bfr[nt] = *(const bf16x8*)&sW[co * KP + ks * 32 + lg * 8];
    }
#pragma unroll
    for (int m = 0; m < MTW; ++m){
      int iy = iyb[m] + dy, ix = ixb[m] + dx;
      bool ok = ((unsigned)iy < (unsigned)HIN) && ((unsigned)ix < (unsigned)WIN);
      int pixi = ok ? (iy * WIN + ix) : 0;
      bf16x8 a = *(const bf16x8*)&sIn[pixi * CP + cib];
      if (!ok) a = ZV;
#pragma unroll
      for (int nt = 0; nt < NT; ++nt)
        acc[m][nt] = __builtin_amdgcn_mfma_f32_16x16x32_bf16(a, bfr[nt], acc[m][nt], 0, 0, 0);
    }
  }

  if constexpr (!NCHW_OUT){
    constexpr int RG = 16 * WAVES;
    __shared__ ushort sOut[RG * COUT];
    size_t obase = (size_t)blockIdx.x * POUT * COUT;
#pragma unroll
    for (int m = 0; m < MTW; ++m){
      if (m) __syncthreads();
#pragma unroll
      for (int nt = 0; nt < NT; ++nt){
        int co = nt * 16 + l15;
#pragma unroll
        for (int r = 0; r < 4; ++r){
          int rl = wid * 16 + lg * 4 + r;
          sOut[rl * COUT + co] = f2bu(gelu_exact(acc[m][nt][r] + bv[nt]));
        }
      }
      __syncthreads();
      for (int t = tid; t < RG * COUT / 8; t += NTH)
        *(uint4*)(out + obase + (size_t)m * RG * COUT + t * 8) = *(const uint4*)&sOut[t * 8];
    }
  } else {
#pragma unroll
    for (int m = 0; m < MTW; ++m){
      int mt = m * WAVES + wid;
#pragma unroll
      for (int nt = 0; nt < NT; ++nt){
        int co = nt * 16 + l15;
#pragma unroll
        for (int r = 0; r < 4; ++r){
          int prow = mt * 16 + lg * 4 + r;
          float v = gelu_exact(acc[m][nt][r] + bv[nt]);
          out[(size_t)blockIdx.x * POUT * COUT + co * POUT + prow] = f2bu(v);
        }
      }
    }
  }
}

// ---------------- encoder FC, split-K MFMA: partial[sl][1040][256] ----------------
__global__ __launch_bounds__(256) void fc_mfma_sk(const ushort* __restrict__ A, const ushort* __restrict__ Wb,
                                                  float* __restrict__ partial){
  __shared__ __align__(16) ushort sA[64][72];
  __shared__ __align__(16) ushort sB[256][72];
  int tid = threadIdx.x;
  int mt = blockIdx.x >> 3, sl = blockIdx.x & 7;       // 17 M-tiles x 8 K-slices
  int M0 = mt * 64;
  int wid = tid >> 6, lane = tid & 63;
  int l15 = lane & 15, lg = lane >> 4;

  f32x4 acc[16] = {};
  for (int i8 = 0; i8 < 8; ++i8){
    int kb = sl * 8 + i8;
#pragma unroll
    for (int i = 0; i < 2; ++i){
      int t = i * 256 + tid;
      int row = t >> 3, c = t & 7;
      int grow = M0 + row; if (grow > 1039) grow = 1039;
      *(uint4*)&sA[row][c * 8] = *(const uint4*)(A + (size_t)grow * 4096 + kb * 64 + c * 8);
    }
#pragma unroll
    for (int i = 0; i < 8; ++i){
      int t = i * 256 + tid;
      int row = t >> 3, c = t & 7;
      *(uint4*)&sB[row][c * 8] = *(const uint4*)(Wb + (size_t)row * 4096 + kb * 64 + c * 8);
    }
    __syncthreads();
#pragma unroll
    for (int ks = 0; ks < 2; ++ks){
      bf16x8 a = *(const bf16x8*)&sA[wid * 16 + l15][ks * 32 + lg * 8];
#pragma unroll
      for (int nt = 0; nt < 16; ++nt){
        bf16x8 b = *(const bf16x8*)&sB[nt * 16 + l15][ks * 32 + lg * 8];
        acc[nt] = __builtin_amdgcn_mfma_f32_16x16x32_bf16(a, b, acc[nt], 0, 0, 0);
      }
    }
    __syncthreads();
  }
#pragma unroll
  for (int nt = 0; nt < 16; ++nt){
    int j = nt * 16 + l15;
#pragma unroll
    for (int r = 0; r < 4; ++r){
      int row = M0 + wid * 16 + lg * 4 + r;
      if (row < 1040) partial[((size_t)sl * 1040 + row) * 256 + j] = acc[nt][r];
    }
  }
}

__global__ void fc_reduce(const float* __restrict__ partial, const float* __restrict__ fcb,
                          float* __restrict__ ml){
  int idx = blockIdx.x * 256 + threadIdx.x;            // 1040*256
  if (idx >= 266240) return;
  float s = fcb[idx & 255];
#pragma unroll
  for (int q = 0; q < 8; ++q) s += partial[(size_t)q * 266240 + idx];
  ml[idx] = s;
}

// ---------------- reparameterization ----------------
__global__ void reparam_kernel(const float* __restrict__ ml, float* __restrict__ z){
  int i = blockIdx.x * 256 + threadIdx.x;
  if (i >= 133120) return;
  uint32_t x0 = 0u, x1 = (uint32_t)i;
  threefry2x32(0u, 42u, x0, x1);
  uint32_t bits = x0 ^ x1;
  uint32_t fb = (bits >> 9) | 0x3f800000u;
  float f = __uint_as_float(fb) - 1.0f;
  const float lo = -0.99999994f;
  float u = f * 2.0f + lo;
  u = fmaxf(lo, u);
  float eps = 1.41421354f * erfinv_f(u);
  int n = i >> 7, d = i & 127;
  float ex = expf(fminf(0.5f * ml[n * 256 + 128 + d], 60.0f));
  z[i] = fmaf(eps, ex, ml[n * 256 + d]);
}

// ---------------- cooperative LSTM: 40 blocks = 5 layers x 8 d-slices ----------------
// Weights staged to LDS once (f32); per wavefront-step grid.sync() hand-off via hbuf.
__global__ __launch_bounds__(256) void lstm_coop(const float* __restrict__ z,
                                                 const ushort* __restrict__ W8,
                                                 const float* __restrict__ bsum4,
                                                 float* __restrict__ hbuf){
  cg::grid_group grid = cg::this_grid();
  int l = blockIdx.x >> 3, dsl = blockIdx.x & 7;
  int tid = threadIdx.x;
  int b = tid >> 4, ds = tid & 15, d = dsl * 16 + ds;

  __shared__ __align__(16) f32x4 sWa[128][16];         // ih gates (i,f,g,o)  32 KB
  __shared__ __align__(16) f32x4 sWb[128][16];         // hh gates            32 KB
  __shared__ float sI[16][132], sH[16][132];           // padded: conflict-free

  for (int i = tid; i < 128 * 16; i += 256){
    int k = i >> 4, dss = i & 15;
    bf16x8 wv = *(const bf16x8*)&W8[((size_t)l * 16384 + (size_t)k * 128 + dsl * 16 + dss) * 8];
    f32x4 wa, wb;
    wa[0] = bu2f((ushort)wv[0]); wa[1] = bu2f((ushort)wv[1]);
    wa[2] = bu2f((ushort)wv[2]); wa[3] = bu2f((ushort)wv[3]);
    wb[0] = bu2f((ushort)wv[4]); wb[1] = bu2f((ushort)wv[5]);
    wb[2] = bu2f((ushort)wv[6]); wb[3] = bu2f((ushort)wv[7]);
    sWa[k][dss] = wa; sWb[k][dss] = wb;
  }
  f32x4 bs = *(const f32x4*)&bsum4[((size_t)l * 128 + d) * 4];
  float c = 0.f;
  __syncthreads();

  for (int wf = 0; wf < 68; ++wf){
    int t = wf - l;
    if (t >= 0 && t < 64){
      for (int i = tid; i < 512; i += 256){            // 512 f32x4 = 2x 16x128
        int bb = i >> 5, cc = (i & 31) * 4;
        const float* src = (l == 0) ? &z[(bb * 65 + t) * 128 + cc]
                                    : &hbuf[(((l - 1) * 64 + t) * 16 + bb) * 128 + cc];
        *(f32x4*)&sI[bb][cc] = *(const f32x4*)src;
        if (t > 0) *(f32x4*)&sH[bb][cc] = *(const f32x4*)&hbuf[((l * 64 + (t - 1)) * 16 + bb) * 128 + cc];
        else       *(f32x4*)&sH[bb][cc] = f32x4{0.f, 0.f, 0.f, 0.f};
      }
      __syncthreads();
      float ai = bs[0], af = bs[1], ag = bs[2], ao = bs[3];
#pragma unroll 8
      for (int k = 0; k < 128; ++k){
        float iv = sI[b][k], hv = sH[b][k];
        f32x4 wa = sWa[k][ds], wb = sWb[k][ds];
        ai = fmaf(iv, wa[0], fmaf(hv, wb[0], ai));
        af = fmaf(iv, wa[1], fmaf(hv, wb[1], af));
        ag = fmaf(iv, wa[2], fmaf(hv, wb[2], ag));
        ao = fmaf(iv, wa[3], fmaf(hv, wb[3], ao));
      }
      float cn = sigmoidf_(af) * c + sigmoidf_(ai) * tanhf(ag);
      float hn = sigmoidf_(ao) * tanhf(cn);
      c = cn;
      hbuf[((l * 64 + t) * 16 + b) * 128 + d] = hn;
    }
    grid.sync();
  }
}

// ---------------- projection + MSE ----------------
__global__ void pred_loss(const float* __restrict__ hbuf, const float* __restrict__ lin_w,
                          const float* __restrict__ lin_b, const float* __restrict__ z,
                          float* __restrict__ partial){
  int blk = blockIdx.x;                                // 16*61
  int b = blk / 61, i = 3 + blk % 61;
  int tid = threadIdx.x;                               // 128
  __shared__ float h5[128];
  h5[tid] = hbuf[((4 * 64 + i) * 16 + b) * 128 + tid];
  __syncthreads();
  float acc = lin_b[tid];
  const float* wr = lin_w + tid * 128;
#pragma unroll 8
  for (int k = 0; k < 128; ++k) acc = fmaf(h5[k], wr[k], acc);
  float zy = z[(b * 65 + i + 1) * 128 + tid];
  float df = acc - zy;
  float v = df * df;
  for (int off = 32; off > 0; off >>= 1) v += __shfl_down(v, off);
  __shared__ float wsum[2];
  if ((tid & 63) == 0) wsum[tid >> 6] = v;
  __syncthreads();
  if (tid == 0) partial[blk] = wsum[0] + wsum[1];
}

__global__ void loss_final(const float* __restrict__ partial, float* __restrict__ out){
  int tid = threadIdx.x;                               // 256
  float v = 0.0f;
  for (int i = tid; i < 976; i += 256) v += partial[i];
  for (int off = 32; off > 0; off >>= 1) v += __shfl_down(v, off);
  __shared__ float s[4];
  if ((tid & 63) == 0) s[tid >> 6] = v;
  __syncthreads();
  if (tid == 0) out[0] = (s[0] + s[1] + s[2] + s[3]) * (1.0f / 124928.0f);
}

extern "C" void kernel_launch(void* const* d_in, const int* in_sizes, int n_in,
                              void* d_out, int out_size, void* d_ws, size_t ws_size,
                              hipStream_t stream){
  const float* x   = (const float*)d_in[0];
  const float* ew1 = (const float*)d_in[1];  const float* eb1 = (const float*)d_in[2];
  const float* ew2 = (const float*)d_in[3];  const float* eb2 = (const float*)d_in[4];
  const float* ew3 = (const float*)d_in[5];  const float* eb3 = (const float*)d_in[6];
  const float* ew4 = (const float*)d_in[7];  const float* eb4 = (const float*)d_in[8];
  const float* ew5 = (const float*)d_in[9];  const float* eb5 = (const float*)d_in[10];
  const float* fcw = (const float*)d_in[11]; const float* fcb = (const float*)d_in[12];
  // d_in[13..24]: decoder params (dead code in the reference) — unused
  const float* Wih = (const float*)d_in[25]; const float* Whh = (const float*)d_in[26];
  const float* bih = (const float*)d_in[27]; const float* bhh = (const float*)d_in[28];
  const float* lw  = (const float*)d_in[29]; const float* lb  = (const float*)d_in[30];

  char* ws = (char*)d_ws;
  size_t off = 0;
  auto alloc = [&](size_t bytes) -> void* {
    void* p = ws + off;
    off = (off + bytes + 255) & ~(size_t)255;
    return p;
  };
  ushort* bufA  = (ushort*)alloc(34078720ull * 2);     // 1040*1024*32 bf16
  ushort* bufB  = (ushort*)alloc(34078720ull * 2);
  ushort* wt2   = (ushort*)alloc(32ull * 296 * 2);
  ushort* wt3   = (ushort*)alloc(64ull * 296 * 2);
  ushort* wt4   = (ushort*)alloc(64ull * 600 * 2);
  ushort* wt5   = (ushort*)alloc(64ull * 600 * 2);
  ushort* fcwB  = (ushort*)alloc(256ull * 4096 * 2);
  ushort* W8    = (ushort*)alloc(5ull * 131072 * 2);
  float*  bsum4 = (float*) alloc(5ull * 512 * 4);
  float*  ml    = (float*) alloc(1040ull * 256 * 4);
  float*  zbuf  = (float*) alloc(1040ull * 128 * 4);
  float*  hbuf  = (float*) alloc(5ull * 64 * 16 * 128 * 4);
  float*  part  = (float*) alloc(976ull * 4);
  float*  fpart = (float*)bufB;                        // fc split-K partials reuse dead bufB (8.5 MB)

  prep_w<<<(32 * 296 + 255) / 256, 256, 0, stream>>>(ew2, wt2, 32, 32, 296);
  prep_w<<<(64 * 296 + 255) / 256, 256, 0, stream>>>(ew3, wt3, 32, 64, 296);
  prep_w<<<(64 * 600 + 255) / 256, 256, 0, stream>>>(ew4, wt4, 64, 64, 600);
  prep_w<<<(64 * 600 + 255) / 256, 256, 0, stream>>>(ew5, wt5, 64, 64, 600);
  prep_fcb<<<4096, 256, 0, stream>>>(fcw, fcwB);
  prep_lstm8<<<320, 256, 0, stream>>>(Wih, Whh, bih, bhh, W8, bsum4);

  conv1_gelu<<<16640, 256, 0, stream>>>(x, ew1, eb1, bufA);
  conv_mfma<32, 32, 32, 32, 1, 8, false><<<1040, 512, 0, stream>>>(bufA, wt2, eb2, bufB);
  conv_mfma<32, 64, 16, 16, 2, 8, false><<<1040, 512, 0, stream>>>(bufB, wt3, eb3, bufA);
  conv_mfma<64, 64, 16, 16, 1, 8, false><<<1040, 512, 0, stream>>>(bufA, wt4, eb4, bufB);
  conv_mfma<64, 64,  8,  8, 2, 4, true ><<<1040, 256, 0, stream>>>(bufB, wt5, eb5, bufA);

  fc_mfma_sk<<<136, 256, 0, stream>>>(bufA, fcwB, fpart);
  fc_reduce<<<1040, 256, 0, stream>>>(fpart, fcb, ml);
  reparam_kernel<<<(133120 + 255) / 256, 256, 0, stream>>>(ml, zbuf);

  {
    void* args[] = {(void*)&zbuf, (void*)&W8, (void*)&bsum4, (void*)&hbuf};
    hipLaunchCooperativeKernel((void*)lstm_coop, dim3(40), dim3(256), args, 0, stream);
  }

  pred_loss<<<976, 128, 0, stream>>>(hbuf, lw, lb, zbuf, part);
  loss_final<<<1, 256, 0, stream>>>(part, (float*)d_out);
}